// Round 2
// baseline (470.972 us; speedup 1.0000x reference)
//
#include <hip/hip_runtime.h>

#define T_  4
#define B_  2
#define C_  384
#define L_  1024
#define H_  8
#define D_  48
#define C2_ 768
#define S_  (B_*C_*L_)   // 786432 elements per time step

// ---------------- K1/K5: mem_update scan over T, emits 0/1 spikes ----------
// ZERO=1 additionally zero-fills zbuf (same footprint) for later atomics.
template <int ZERO>
__global__ __launch_bounds__(256) void spike_scan(const float* __restrict__ src,
                                                  float* __restrict__ dst,
                                                  float* __restrict__ zbuf) {
    int i = blockIdx.x * 256 + threadIdx.x;
    float mem = 0.f, s = 0.f;
#pragma unroll
    for (int t = 0; t < T_; t++) {
        mem = mem * 0.25f * (1.f - s) + src[(size_t)t * S_ + i];
        s = (mem > 0.5f) ? 1.f : 0.f;
        dst[(size_t)t * S_ + i] = s;
        if (ZERO) zbuf[(size_t)t * S_ + i] = 0.f;
    }
}

// ---------------- K2/K6: Y = BN(W @ X) (+ residual), K=384 -----------------
// W: (M,384) row-major; X: (batch, 384, 1024); out: (batch, M, 1024)
template <int RES>
__global__ __launch_bounds__(256) void gemm_bn(
    const float* __restrict__ W, const float* __restrict__ X,
    const float* __restrict__ gamma, const float* __restrict__ beta,
    const float* __restrict__ mean, const float* __restrict__ var,
    const float* __restrict__ res, float* __restrict__ out, int M) {
    __shared__ float W_s[16][68];   // [k][m], padded
    __shared__ float X_s[16][64];   // [k][n]
    const int tid = threadIdx.x;
    const int batch = blockIdx.y;
    const int mt = blockIdx.x >> 4, nt = blockIdx.x & 15;
    const int om = mt * 64, ln = nt * 64;
    const float* Xb = X + (size_t)batch * C_ * L_;
    const int tx = tid & 15, ty = tid >> 4;

    const int e = tid * 4;
    const int wo = e >> 4, wc = e & 15;    // W tile: 64 rows x 16 k
    const int xc = e >> 6, xl = e & 63;    // X tile: 16 k x 64 cols

    float acc[4][4] = {};
    for (int ck = 0; ck < C_; ck += 16) {
        float4 wv = *(const float4*)(W + (size_t)(om + wo) * C_ + ck + wc);
        float4 xv = *(const float4*)(Xb + (size_t)(ck + xc) * L_ + ln + xl);
        W_s[wc + 0][wo] = wv.x; W_s[wc + 1][wo] = wv.y;
        W_s[wc + 2][wo] = wv.z; W_s[wc + 3][wo] = wv.w;
        *(float4*)&X_s[xc][xl] = xv;
        __syncthreads();
#pragma unroll
        for (int kk = 0; kk < 16; kk++) {
            float av[4], bv[4];
            *(float4*)av = *(const float4*)&W_s[kk][ty * 4];
            *(float4*)bv = *(const float4*)&X_s[kk][tx * 4];
#pragma unroll
            for (int i = 0; i < 4; i++)
#pragma unroll
                for (int j = 0; j < 4; j++) acc[i][j] += av[i] * bv[j];
        }
        __syncthreads();
    }
#pragma unroll
    for (int i = 0; i < 4; i++) {
        const int o = om + ty * 4 + i;
        const float inv = gamma[o] / sqrtf(var[o] + 1e-5f);
        const float sh = beta[o] - mean[o] * inv;
        float4 r;
        r.x = acc[i][0] * inv + sh; r.y = acc[i][1] * inv + sh;
        r.z = acc[i][2] * inv + sh; r.w = acc[i][3] * inv + sh;
        const size_t off = ((size_t)batch * M + o) * L_ + ln + tx * 4;
        if (RES) {
            float4 rv = *(const float4*)(res + off);
            r.x += rv.x; r.y += rv.y; r.z += rv.z; r.w += rv.w;
        }
        *(float4*)(out + off) = r;
    }
}

// ---------------- K3: attn = y1^T @ xr, t-scan in registers, bit-packed ----
__global__ __launch_bounds__(256) void attn_spike(
    const float* __restrict__ y, const float* __restrict__ xs,
    unsigned* __restrict__ bits) {
    __shared__ float A_s[D_][64];       // y1 [d][l]
    __shared__ float B_s[D_][64];       // xr [d][m]
    __shared__ unsigned bits_s[64][2];
    const int tid = threadIdx.x;
    const int b = blockIdx.y >> 3, h = blockIdx.y & 7;
    const int lbase = (blockIdx.x >> 4) * 64, mbase = (blockIdx.x & 15) * 64;
    const int tx = tid & 15, ty = tid >> 4;

    float mem[4][4], sp[4][4];
#pragma unroll
    for (int i = 0; i < 4; i++)
#pragma unroll
        for (int j = 0; j < 4; j++) { mem[i][j] = 0.f; sp[i][j] = 0.f; }

    for (int t = 0; t < T_; t++) {
#pragma unroll
        for (int p = 0; p < 3; p++) {
            const int ee = p * 1024 + tid * 4;
            const int dd = ee >> 6, col = ee & 63;
            *(float4*)&A_s[dd][col] =
                *(const float4*)(y + ((size_t)(t * B_ + b) * C2_ + h * 96 + dd) * L_ + lbase + col);
            *(float4*)&B_s[dd][col] =
                *(const float4*)(xs + ((size_t)(t * B_ + b) * C_ + h * D_ + dd) * L_ + mbase + col);
        }
        if (tid < 128) bits_s[tid >> 1][tid & 1] = 0u;
        __syncthreads();

        float acc[4][4] = {};
#pragma unroll 4
        for (int dd = 0; dd < D_; dd++) {
            float av[4], bv[4];
            *(float4*)av = *(const float4*)&A_s[dd][ty * 4];
            *(float4*)bv = *(const float4*)&B_s[dd][tx * 4];
#pragma unroll
            for (int i = 0; i < 4; i++)
#pragma unroll
                for (int j = 0; j < 4; j++) acc[i][j] += av[i] * bv[j];
        }

#pragma unroll
        for (int i = 0; i < 4; i++) {
            unsigned nib = 0;
#pragma unroll
            for (int j = 0; j < 4; j++) {
                mem[i][j] = mem[i][j] * 0.25f * (1.f - sp[i][j]) + acc[i][j];
                sp[i][j] = (mem[i][j] > 0.5f) ? 1.f : 0.f;
                if (mem[i][j] > 0.5f) nib |= (1u << j);
            }
            atomicOr(&bits_s[ty * 4 + i][tx >> 3], nib << ((tx & 7) * 4));
        }
        __syncthreads();
        if (tid < 128) {
            const int l = tid >> 1, w = tid & 1;
            const size_t wi =
                ((size_t)((t * B_ + b) * H_ + h) * L_ + lbase + l) * (L_ / 32) + (mbase >> 5) + w;
            bits[wi] = bits_s[l][w];
        }
        __syncthreads();
    }
}

// ---------------- K4: outpre[d,m] += sum_{l in chunk} y2[d,l]*spike(l,m) ---
// grid: (mtiles=8, tbh=64, lchunks=4); fp32 atomicAdd combine (outpre pre-zeroed)
__global__ __launch_bounds__(256) void attn_out(
    const float* __restrict__ y, const unsigned* __restrict__ bits,
    float* __restrict__ outpre) {
    __shared__ float y2_s[D_][64];      // [d][l]
    __shared__ unsigned mask_s[64][4];  // [l][word], 128 m-bits
    const int tid = threadIdx.x;
    const int tbh = blockIdx.y;
    const int t = tbh >> 4, b = (tbh >> 3) & 1, h = tbh & 7;
    const int mbase = blockIdx.x * 128;
    const int lbase = blockIdx.z * 256;
    const int tx = tid & 31, ty = tid >> 5;
    const int sh = (tx & 7) * 4;

    float acc[6][4] = {};
    for (int lt = lbase; lt < lbase + 256; lt += 64) {
#pragma unroll
        for (int p = 0; p < 3; p++) {
            const int ee = p * 1024 + tid * 4;
            const int dd = ee >> 6, col = ee & 63;
            *(float4*)&y2_s[dd][col] =
                *(const float4*)(y + ((size_t)(t * B_ + b) * C2_ + h * 96 + 48 + dd) * L_ + lt + col);
        }
        {
            const int l = tid >> 2, w = tid & 3;
            mask_s[l][w] =
                bits[((size_t)((t * B_ + b) * H_ + h) * L_ + lt + l) * (L_ / 32) + (mbase >> 5) + w];
        }
        __syncthreads();

        for (int l0 = 0; l0 < 64; l0 += 4) {
            float yv[6][4];
#pragma unroll
            for (int dd = 0; dd < 6; dd++)
                *(float4*)yv[dd] = *(const float4*)&y2_s[ty * 6 + dd][l0];
#pragma unroll
            for (int lo = 0; lo < 4; lo++) {
                const unsigned bw = mask_s[l0 + lo][tx >> 3];
                float f[4];
#pragma unroll
                for (int j = 0; j < 4; j++) f[j] = (float)((bw >> (sh + j)) & 1u);
#pragma unroll
                for (int dd = 0; dd < 6; dd++)
#pragma unroll
                    for (int j = 0; j < 4; j++) acc[dd][j] += yv[dd][lo] * f[j];
            }
        }
        __syncthreads();
    }
#pragma unroll
    for (int dd = 0; dd < 6; dd++) {
        const int c = h * D_ + ty * 6 + dd;
        float* dst = outpre + ((size_t)(t * B_ + b) * C_ + c) * L_ + mbase + tx * 4;
#pragma unroll
        for (int j = 0; j < 4; j++) atomicAdd(dst + j, acc[dd][j]);
    }
}

extern "C" void kernel_launch(void* const* d_in, const int* in_sizes, int n_in,
                              void* d_out, int out_size, void* d_ws, size_t ws_size,
                              hipStream_t stream) {
    const float* x   = (const float*)d_in[0];
    const float* W_w = (const float*)d_in[1];
    const float* g1  = (const float*)d_in[2];
    const float* b1  = (const float*)d_in[3];
    const float* m1  = (const float*)d_in[4];
    const float* v1  = (const float*)d_in[5];
    const float* pw  = (const float*)d_in[6];
    const float* g2  = (const float*)d_in[7];
    const float* b2  = (const float*)d_in[8];
    const float* m2  = (const float*)d_in[9];
    const float* v2  = (const float*)d_in[10];

    float* ws = (float*)d_ws;
    float*    xs     = ws;                              // 3,145,728 f
    float*    y      = ws + 3145728;                    // 6,291,456 f
    unsigned* bits   = (unsigned*)(ws + 9437184);       // 2,097,152 words
    float*    outpre = ws + 11534336;                   // 3,145,728 f
    float*    outs   = xs;                              // alias (xs dead after K3)
    float*    out    = (float*)d_out;                   // total ws use: 56 MB

    // 1) xs = spikes(mem_update(x)); also zero outpre for K4's atomics
    spike_scan<1><<<dim3(S_ / 256), 256, 0, stream>>>(x, xs, outpre);
    // 2) y = BN1(W_w @ xs)     M=768 -> 12 mtiles x 16 ntiles
    gemm_bn<0><<<dim3(192, 8), 256, 0, stream>>>(W_w, xs, g1, b1, m1, v1, nullptr, y, C2_);
    // 3) attn spikes (scan over t in registers), bit-packed
    attn_spike<<<dim3(256, 16), 256, 0, stream>>>(y, xs, bits);
    // 4) outpre += y2 @ attn_spikes  (l split 4 ways, atomic combine)
    attn_out<<<dim3(8, 64, 4), 256, 0, stream>>>(y, bits, outpre);
    // 5) outs = spikes(mem_update(outpre))
    spike_scan<0><<<dim3(S_ / 256), 256, 0, stream>>>(outpre, outs, nullptr);
    // 6) out = BN2(proj_w @ outs) + x    M=384 -> 6 mtiles x 16 ntiles
    gemm_bn<1><<<dim3(96, 8), 256, 0, stream>>>(pw, outs, g2, b2, m2, v2, x, out, C_);
}

// Round 3
// 390.309 us; speedup vs baseline: 1.2067x; 1.2067x over previous
//
#include <hip/hip_runtime.h>

#define T_  4
#define B_  2
#define C_  384
#define L_  1024
#define H_  8
#define D_  48
#define C2_ 768
#define S_  (B_*C_*L_)   // 786432 elements per time step

// ---------------- K1/K5: mem_update scan over T, emits 0/1 spikes ----------
// SUM2=1: input is src[i]+src2[i] (used to combine split-L partials for free)
template <int SUM2>
__global__ __launch_bounds__(256) void spike_scan(const float* __restrict__ src,
                                                  const float* __restrict__ src2,
                                                  float* __restrict__ dst) {
    int i = blockIdx.x * 256 + threadIdx.x;
    float mem = 0.f, s = 0.f;
#pragma unroll
    for (int t = 0; t < T_; t++) {
        float v = src[(size_t)t * S_ + i];
        if (SUM2) v += src2[(size_t)t * S_ + i];
        mem = mem * 0.25f * (1.f - s) + v;
        s = (mem > 0.5f) ? 1.f : 0.f;
        dst[(size_t)t * S_ + i] = s;
    }
}

// ---------------- K2/K6: Y = BN(W @ X) (+ residual), K=384 -----------------
// W: (M,384) row-major; X: (batch, 384, 1024); out: (batch, M, 1024)
template <int RES>
__global__ __launch_bounds__(256) void gemm_bn(
    const float* __restrict__ W, const float* __restrict__ X,
    const float* __restrict__ gamma, const float* __restrict__ beta,
    const float* __restrict__ mean, const float* __restrict__ var,
    const float* __restrict__ res, float* __restrict__ out, int M) {
    __shared__ float W_s[16][68];   // [k][m], padded
    __shared__ float X_s[16][64];   // [k][n]
    const int tid = threadIdx.x;
    const int batch = blockIdx.y;
    const int mt = blockIdx.x >> 4, nt = blockIdx.x & 15;
    const int om = mt * 64, ln = nt * 64;
    const float* Xb = X + (size_t)batch * C_ * L_;
    const int tx = tid & 15, ty = tid >> 4;

    const int e = tid * 4;
    const int wo = e >> 4, wc = e & 15;    // W tile: 64 rows x 16 k
    const int xc = e >> 6, xl = e & 63;    // X tile: 16 k x 64 cols

    float acc[4][4] = {};
    for (int ck = 0; ck < C_; ck += 16) {
        float4 wv = *(const float4*)(W + (size_t)(om + wo) * C_ + ck + wc);
        float4 xv = *(const float4*)(Xb + (size_t)(ck + xc) * L_ + ln + xl);
        W_s[wc + 0][wo] = wv.x; W_s[wc + 1][wo] = wv.y;
        W_s[wc + 2][wo] = wv.z; W_s[wc + 3][wo] = wv.w;
        *(float4*)&X_s[xc][xl] = xv;
        __syncthreads();
#pragma unroll
        for (int kk = 0; kk < 16; kk++) {
            float av[4], bv[4];
            *(float4*)av = *(const float4*)&W_s[kk][ty * 4];
            *(float4*)bv = *(const float4*)&X_s[kk][tx * 4];
#pragma unroll
            for (int i = 0; i < 4; i++)
#pragma unroll
                for (int j = 0; j < 4; j++) acc[i][j] += av[i] * bv[j];
        }
        __syncthreads();
    }
#pragma unroll
    for (int i = 0; i < 4; i++) {
        const int o = om + ty * 4 + i;
        const float inv = gamma[o] / sqrtf(var[o] + 1e-5f);
        const float sh = beta[o] - mean[o] * inv;
        float4 r;
        r.x = acc[i][0] * inv + sh; r.y = acc[i][1] * inv + sh;
        r.z = acc[i][2] * inv + sh; r.w = acc[i][3] * inv + sh;
        const size_t off = ((size_t)batch * M + o) * L_ + ln + tx * 4;
        if (RES) {
            float4 rv = *(const float4*)(res + off);
            r.x += rv.x; r.y += rv.y; r.z += rv.z; r.w += rv.w;
        }
        *(float4*)(out + off) = r;
    }
}

// ---------------- K3: attn = y1^T @ xr, t-scan in registers, bit-packed ----
__global__ __launch_bounds__(256) void attn_spike(
    const float* __restrict__ y, const float* __restrict__ xs,
    unsigned* __restrict__ bits) {
    __shared__ float A_s[D_][64];       // y1 [d][l]
    __shared__ float B_s[D_][64];       // xr [d][m]
    __shared__ unsigned bits_s[64][2];
    const int tid = threadIdx.x;
    const int b = blockIdx.y >> 3, h = blockIdx.y & 7;
    const int lbase = (blockIdx.x >> 4) * 64, mbase = (blockIdx.x & 15) * 64;
    const int tx = tid & 15, ty = tid >> 4;

    float mem[4][4], sp[4][4];
#pragma unroll
    for (int i = 0; i < 4; i++)
#pragma unroll
        for (int j = 0; j < 4; j++) { mem[i][j] = 0.f; sp[i][j] = 0.f; }

    for (int t = 0; t < T_; t++) {
#pragma unroll
        for (int p = 0; p < 3; p++) {
            const int ee = p * 1024 + tid * 4;
            const int dd = ee >> 6, col = ee & 63;
            *(float4*)&A_s[dd][col] =
                *(const float4*)(y + ((size_t)(t * B_ + b) * C2_ + h * 96 + dd) * L_ + lbase + col);
            *(float4*)&B_s[dd][col] =
                *(const float4*)(xs + ((size_t)(t * B_ + b) * C_ + h * D_ + dd) * L_ + mbase + col);
        }
        if (tid < 128) bits_s[tid >> 1][tid & 1] = 0u;
        __syncthreads();

        float acc[4][4] = {};
#pragma unroll 4
        for (int dd = 0; dd < D_; dd++) {
            float av[4], bv[4];
            *(float4*)av = *(const float4*)&A_s[dd][ty * 4];
            *(float4*)bv = *(const float4*)&B_s[dd][tx * 4];
#pragma unroll
            for (int i = 0; i < 4; i++)
#pragma unroll
                for (int j = 0; j < 4; j++) acc[i][j] += av[i] * bv[j];
        }

#pragma unroll
        for (int i = 0; i < 4; i++) {
            unsigned nib = 0;
#pragma unroll
            for (int j = 0; j < 4; j++) {
                mem[i][j] = mem[i][j] * 0.25f * (1.f - sp[i][j]) + acc[i][j];
                sp[i][j] = (mem[i][j] > 0.5f) ? 1.f : 0.f;
                if (mem[i][j] > 0.5f) nib |= (1u << j);
            }
            atomicOr(&bits_s[ty * 4 + i][tx >> 3], nib << ((tx & 7) * 4));
        }
        __syncthreads();
        if (tid < 128) {
            const int l = tid >> 1, w = tid & 1;
            const size_t wi =
                ((size_t)((t * B_ + b) * H_ + h) * L_ + lbase + l) * (L_ / 32) + (mbase >> 5) + w;
            bits[wi] = bits_s[l][w];
        }
        __syncthreads();
    }
}

// ---------------- K4: part[z][d,m] = sum_{l in half z} y2[d,l]*spike(l,m) --
// grid: (mtiles=8, tbh=64, lhalf=2); plain float4 stores to disjoint partials
__global__ __launch_bounds__(256) void attn_out(
    const float* __restrict__ y, const unsigned* __restrict__ bits,
    float* __restrict__ p0, float* __restrict__ p1) {
    __shared__ float y2_s[D_][64];      // [d][l]
    __shared__ unsigned mask_s[64][4];  // [l][word], 128 m-bits
    const int tid = threadIdx.x;
    const int tbh = blockIdx.y;
    const int t = tbh >> 4, b = (tbh >> 3) & 1, h = tbh & 7;
    const int mbase = blockIdx.x * 128;
    const int lbase = blockIdx.z * 512;
    const int tx = tid & 31, ty = tid >> 5;
    const int sh = (tx & 7) * 4;

    float acc[6][4] = {};
    for (int lt = lbase; lt < lbase + 512; lt += 64) {
#pragma unroll
        for (int p = 0; p < 3; p++) {
            const int ee = p * 1024 + tid * 4;
            const int dd = ee >> 6, col = ee & 63;
            *(float4*)&y2_s[dd][col] =
                *(const float4*)(y + ((size_t)(t * B_ + b) * C2_ + h * 96 + 48 + dd) * L_ + lt + col);
        }
        {
            const int l = tid >> 2, w = tid & 3;
            mask_s[l][w] =
                bits[((size_t)((t * B_ + b) * H_ + h) * L_ + lt + l) * (L_ / 32) + (mbase >> 5) + w];
        }
        __syncthreads();

        for (int l0 = 0; l0 < 64; l0 += 4) {
            float yv[6][4];
#pragma unroll
            for (int dd = 0; dd < 6; dd++)
                *(float4*)yv[dd] = *(const float4*)&y2_s[ty * 6 + dd][l0];
#pragma unroll
            for (int lo = 0; lo < 4; lo++) {
                const unsigned bw = mask_s[l0 + lo][tx >> 3];
                float f[4];
#pragma unroll
                for (int j = 0; j < 4; j++) f[j] = (float)((bw >> (sh + j)) & 1u);
#pragma unroll
                for (int dd = 0; dd < 6; dd++)
#pragma unroll
                    for (int j = 0; j < 4; j++) acc[dd][j] += yv[dd][lo] * f[j];
            }
        }
        __syncthreads();
    }
    float* part = blockIdx.z ? p1 : p0;
#pragma unroll
    for (int dd = 0; dd < 6; dd++) {
        const int c = h * D_ + ty * 6 + dd;
        float4 r = {acc[dd][0], acc[dd][1], acc[dd][2], acc[dd][3]};
        *(float4*)(part + ((size_t)(t * B_ + b) * C_ + c) * L_ + mbase + tx * 4) = r;
    }
}

extern "C" void kernel_launch(void* const* d_in, const int* in_sizes, int n_in,
                              void* d_out, int out_size, void* d_ws, size_t ws_size,
                              hipStream_t stream) {
    const float* x   = (const float*)d_in[0];
    const float* W_w = (const float*)d_in[1];
    const float* g1  = (const float*)d_in[2];
    const float* b1  = (const float*)d_in[3];
    const float* m1  = (const float*)d_in[4];
    const float* v1  = (const float*)d_in[5];
    const float* pw  = (const float*)d_in[6];
    const float* g2  = (const float*)d_in[7];
    const float* b2  = (const float*)d_in[8];
    const float* m2  = (const float*)d_in[9];
    const float* v2  = (const float*)d_in[10];

    float* ws = (float*)d_ws;
    float*    xs     = ws;                              // 3,145,728 f
    float*    y      = ws + 3145728;                    // 6,291,456 f
    unsigned* bits   = (unsigned*)(ws + 9437184);       // 2,097,152 words
    float*    outpre = ws + 11534336;                   // 3,145,728 f (partial 0)
    float*    part1  = xs;                              // partial 1 aliases xs (dead after K3)
    float*    outs   = xs;                              // K5 out aliases part1 (elementwise-safe)
    float*    out    = (float*)d_out;                   // total ws use: 56 MB

    // 1) xs = spikes(mem_update(x))
    spike_scan<0><<<dim3(S_ / 256), 256, 0, stream>>>(x, nullptr, xs);
    // 2) y = BN1(W_w @ xs)     M=768 -> 12 mtiles x 16 ntiles
    gemm_bn<0><<<dim3(192, 8), 256, 0, stream>>>(W_w, xs, g1, b1, m1, v1, nullptr, y, C2_);
    // 3) attn spikes (scan over t in registers), bit-packed
    attn_spike<<<dim3(256, 16), 256, 0, stream>>>(y, xs, bits);
    // 4) {outpre, part1} = y2 @ attn_spikes over each L-half (plain stores)
    attn_out<<<dim3(8, 64, 2), 256, 0, stream>>>(y, bits, outpre, part1);
    // 5) outs = spikes(mem_update(outpre + part1))
    spike_scan<1><<<dim3(S_ / 256), 256, 0, stream>>>(outpre, part1, outs);
    // 6) out = BN2(proj_w @ outs) + x    M=384 -> 6 mtiles x 16 ntiles
    gemm_bn<1><<<dim3(96, 8), 256, 0, stream>>>(pw, outs, g2, b2, m2, v2, x, out, C_);
}

// Round 4
// 267.037 us; speedup vs baseline: 1.7637x; 1.4616x over previous
//
#include <hip/hip_runtime.h>

#define T_  4
#define B_  2
#define C_  384
#define L_  1024
#define H_  8
#define C2_ 768
#define S_  (B_*C_*L_)

typedef __attribute__((ext_vector_type(8))) short short8;
typedef __attribute__((ext_vector_type(4))) float floatx4;

__device__ __forceinline__ unsigned bf16_rne(float v) {
    unsigned u = __float_as_uint(v);
    u += 0x7FFFu + ((u >> 16) & 1u);
    return u >> 16;
}
__device__ __forceinline__ float bf16_to_f(unsigned h) { return __uint_as_float(h << 16); }
// v = hi + mid + lo + eps, |eps| <= 2^-27 |v|
__device__ __forceinline__ void split3(float v, unsigned& hi, unsigned& mi, unsigned& lo) {
    hi = bf16_rne(v);
    float r1 = v - bf16_to_f(hi);
    mi = bf16_rne(r1);
    float r2 = r1 - bf16_to_f(mi);
    lo = bf16_rne(r2);
}

// ============ K1/K5: mem_update scan over T + bf16 spike transpose =========
// src fp32 [t][b][C][L]  ->  dstT bf16(0/1) [t][b][L][C]
__global__ __launch_bounds__(256) void scan_transpose(const float* __restrict__ src,
                                                      unsigned short* __restrict__ dstT) {
    __shared__ unsigned short tile[64][72];
    const int tid = threadIdx.x;
    const int l0 = blockIdx.x * 64, c0 = blockIdx.y * 64, b = blockIdx.z;
    const int row = tid >> 2, seg = tid & 3;
    float mem[16], sp[16];
#pragma unroll
    for (int e = 0; e < 16; e++) { mem[e] = 0.f; sp[e] = 0.f; }
    for (int t = 0; t < T_; t++) {
        const size_t base = ((size_t)((t*B_ + b)*C_ + c0 + row))*L_ + l0 + seg*16;
#pragma unroll
        for (int qq = 0; qq < 4; qq++) {
            float4 v = *(const float4*)(src + base + qq*4);
            float vv[4] = {v.x, v.y, v.z, v.w};
            unsigned bs[4];
#pragma unroll
            for (int s = 0; s < 4; s++) {
                int e = qq*4 + s;
                mem[e] = mem[e]*0.25f*(1.f - sp[e]) + vv[s];
                bool sb = mem[e] > 0.5f;
                sp[e] = sb ? 1.f : 0.f;
                bs[s] = sb ? 0x3F80u : 0u;
            }
            *(unsigned*)&tile[row][seg*16 + qq*4]     = bs[0] | (bs[1] << 16);
            *(unsigned*)&tile[row][seg*16 + qq*4 + 2] = bs[2] | (bs[3] << 16);
        }
        __syncthreads();
        {
            const int lr = tid >> 2, cs = tid & 3;
#pragma unroll
            for (int sub = 0; sub < 2; sub++) {
                unsigned wv[4];
#pragma unroll
                for (int p = 0; p < 4; p++) {
                    unsigned e0 = tile[cs*16 + sub*8 + p*2][lr];
                    unsigned e1 = tile[cs*16 + sub*8 + p*2 + 1][lr];
                    wv[p] = e0 | (e1 << 16);
                }
                uint4 o; o.x = wv[0]; o.y = wv[1]; o.z = wv[2]; o.w = wv[3];
                *(uint4*)(dstT + ((size_t)(t*B_ + b)*L_ + l0 + lr)*C_ + c0 + cs*16 + sub*8) = o;
            }
        }
        __syncthreads();
    }
}

// ============ K2: y = BN1(W @ xs) via MFMA, W 3-way split ===================
// out: y1 transposed [tb][l][384] (hm uint + lo u16), y2 natural [tb][384][l]
__global__ __launch_bounds__(256) void gemm1_mfma(
    const float* __restrict__ W, const unsigned short* __restrict__ xsT,
    const float* __restrict__ g, const float* __restrict__ be,
    const float* __restrict__ mn, const float* __restrict__ vr,
    unsigned* __restrict__ y1hm, unsigned short* __restrict__ y1lo,
    unsigned* __restrict__ y2hm, unsigned short* __restrict__ y2lo) {
    __shared__ unsigned short A_hi[96][40], A_mi[96][40], A_lo[96][40];
    __shared__ unsigned short B_s[128][40];
    const int tid = threadIdx.x;
    const int tb = blockIdx.y;
    const int mt = blockIdx.x >> 3, lt = blockIdx.x & 7;
    const int l0 = lt * 128;
    const int w = tid >> 6, lane = tid & 63;
    const int q = lane >> 4, n15 = lane & 15;
    const int mw = (w & 1) * 48, lw = (w >> 1) * 64;

    floatx4 acc[3][4];
#pragma unroll
    for (int i = 0; i < 3; i++)
#pragma unroll
        for (int j = 0; j < 4; j++) acc[i][j] = (floatx4){0.f,0.f,0.f,0.f};

    for (int ck = 0; ck < C_; ck += 32) {
        for (int s = tid; s < 768; s += 256) {
            int r = s >> 3, kq = s & 7;
            float4 wv = *(const float4*)(W + (size_t)(mt*96 + r)*C_ + ck + kq*4);
            float ww[4] = {wv.x, wv.y, wv.z, wv.w};
            union { unsigned short us[4]; uint2 u2; } ch, cm, cl;
#pragma unroll
            for (int e = 0; e < 4; e++) {
                unsigned hh, mm, ll; split3(ww[e], hh, mm, ll);
                ch.us[e] = (unsigned short)hh; cm.us[e] = (unsigned short)mm; cl.us[e] = (unsigned short)ll;
            }
            *(uint2*)&A_hi[r][kq*4] = ch.u2;
            *(uint2*)&A_mi[r][kq*4] = cm.u2;
            *(uint2*)&A_lo[r][kq*4] = cl.u2;
        }
        for (int s = tid; s < 512; s += 256) {
            int r = s >> 2, c4 = s & 3;
            uint4 u = *(const uint4*)(xsT + ((size_t)tb*L_ + l0 + r)*C_ + ck + c4*8);
            *(uint4*)&B_s[r][c4*8] = u;
        }
        __syncthreads();
        short8 bb[4];
#pragma unroll
        for (int in = 0; in < 4; in++)
            bb[in] = *(short8*)&B_s[lw + in*16 + n15][q*8];
#pragma unroll
        for (int im = 0; im < 3; im++) {
            short8 ah = *(short8*)&A_hi[mw + im*16 + n15][q*8];
            short8 am = *(short8*)&A_mi[mw + im*16 + n15][q*8];
            short8 al = *(short8*)&A_lo[mw + im*16 + n15][q*8];
#pragma unroll
            for (int in = 0; in < 4; in++) {
                acc[im][in] = __builtin_amdgcn_mfma_f32_16x16x32_bf16(ah, bb[in], acc[im][in], 0,0,0);
                acc[im][in] = __builtin_amdgcn_mfma_f32_16x16x32_bf16(am, bb[in], acc[im][in], 0,0,0);
                acc[im][in] = __builtin_amdgcn_mfma_f32_16x16x32_bf16(al, bb[in], acc[im][in], 0,0,0);
            }
        }
        __syncthreads();
    }
#pragma unroll
    for (int im = 0; im < 3; im++)
#pragma unroll
        for (int r = 0; r < 4; r++) {
            int og = mw + im*16 + q*4 + r;              // 0..95, wave-uniform half
            int o = mt*96 + og;
            float inv = g[o] / sqrtf(vr[o] + 1e-5f);
            float sh = be[o] - mn[o]*inv;
#pragma unroll
            for (int in = 0; in < 4; in++) {
                int l = l0 + lw + in*16 + n15;
                float v = acc[im][in][r]*inv + sh;
                unsigned hh, mm, ll; split3(v, hh, mm, ll);
                unsigned hm = hh | (mm << 16);
                if (og < 48) {
                    size_t idx = ((size_t)tb*L_ + l)*C_ + mt*48 + og;
                    y1hm[idx] = hm; y1lo[idx] = (unsigned short)ll;
                } else {
                    size_t idx = ((size_t)tb*C_ + mt*48 + og - 48)*L_ + l;
                    y2hm[idx] = hm; y2lo[idx] = (unsigned short)ll;
                }
            }
        }
}

// ============ K3: attn = y1^T @ xr (MFMA), t-scan in regs, bits [m][l/32] ==
__global__ __launch_bounds__(256) void attn_spike_mfma(
    const unsigned* __restrict__ y1hm, const unsigned short* __restrict__ y1lo,
    const unsigned short* __restrict__ xsT, unsigned* __restrict__ bits) {
    __shared__ unsigned short A_hi[64][72], A_mi[64][72], A_lo[64][72], B_s[64][72];
    __shared__ unsigned bits_s[64][2];
    const int tid = threadIdx.x;
    const int b = blockIdx.y >> 3, h = blockIdx.y & 7;
    const int lbase = (blockIdx.x >> 4)*64, mbase = (blockIdx.x & 15)*64;
    const int w = tid >> 6, lane = tid & 63;
    const int q = lane >> 4, n15 = lane & 15;
    const int lw = (w & 1)*32, mw = (w >> 1)*32;

    // zero K-pad cols 48..63 once (K=48 padded to 64)
    for (int s = tid; s < 512; s += 256) {
        int arr = s >> 7, rem = s & 127, r = rem >> 1, hf = rem & 1;
        unsigned short* p = arr == 0 ? &A_hi[r][48 + hf*8]
                          : arr == 1 ? &A_mi[r][48 + hf*8]
                          : arr == 2 ? &A_lo[r][48 + hf*8]
                                     : &B_s[r][48 + hf*8];
        uint4 z; z.x = z.y = z.z = z.w = 0u;
        *(uint4*)p = z;
    }

    floatx4 acc[2][2], memv[2][2];
    float spv[2][2][4];
#pragma unroll
    for (int i = 0; i < 2; i++)
#pragma unroll
        for (int j = 0; j < 2; j++) {
            acc[i][j] = (floatx4){0.f,0.f,0.f,0.f};
            memv[i][j] = (floatx4){0.f,0.f,0.f,0.f};
#pragma unroll
            for (int r = 0; r < 4; r++) spv[i][j][r] = 0.f;
        }

    for (int t = 0; t < T_; t++) {
        const int tb = t*B_ + b;
        for (int s = tid; s < 1536; s += 256) {         // stage A (de-interleave y1)
            int r = s / 24, c2 = s % 24;
            size_t idx = ((size_t)tb*L_ + lbase + r)*C_ + h*48 + c2*2;
            uint2 u = *(const uint2*)(y1hm + idx);
            unsigned ul = *(const unsigned*)(y1lo + idx);
            *(unsigned*)&A_hi[r][c2*2] = (u.x & 0xFFFFu) | (u.y << 16);
            *(unsigned*)&A_mi[r][c2*2] = (u.x >> 16) | (u.y & 0xFFFF0000u);
            *(unsigned*)&A_lo[r][c2*2] = ul;
        }
        for (int s = tid; s < 384; s += 256) {          // stage B (xr rows)
            int r = s / 6, sg = s % 6;
            uint4 u = *(const uint4*)(xsT + ((size_t)tb*L_ + mbase + r)*C_ + h*48 + sg*8);
            *(uint4*)&B_s[r][sg*8] = u;
        }
        if (tid < 128) bits_s[tid >> 1][tid & 1] = 0u;
        __syncthreads();
#pragma unroll
        for (int kc = 0; kc < 64; kc += 32) {
            short8 ah[2], am[2], al[2], bb[2];
#pragma unroll
            for (int i = 0; i < 2; i++) {
                int ra = lw + i*16 + n15, rb = mw + i*16 + n15;
                ah[i] = *(short8*)&A_hi[ra][kc + q*8];
                am[i] = *(short8*)&A_mi[ra][kc + q*8];
                al[i] = *(short8*)&A_lo[ra][kc + q*8];
                bb[i] = *(short8*)&B_s[rb][kc + q*8];
            }
#pragma unroll
            for (int i = 0; i < 2; i++)
#pragma unroll
                for (int j = 0; j < 2; j++) {
                    acc[i][j] = __builtin_amdgcn_mfma_f32_16x16x32_bf16(ah[i], bb[j], acc[i][j], 0,0,0);
                    acc[i][j] = __builtin_amdgcn_mfma_f32_16x16x32_bf16(am[i], bb[j], acc[i][j], 0,0,0);
                    acc[i][j] = __builtin_amdgcn_mfma_f32_16x16x32_bf16(al[i], bb[j], acc[i][j], 0,0,0);
                }
        }
#pragma unroll
        for (int i = 0; i < 2; i++)
#pragma unroll
            for (int j = 0; j < 2; j++) {
                unsigned nib = 0;
#pragma unroll
                for (int r = 0; r < 4; r++) {
                    float m = memv[i][j][r]*0.25f*(1.f - spv[i][j][r]) + acc[i][j][r];
                    memv[i][j][r] = m;
                    bool sb = m > 0.5f;
                    spv[i][j][r] = sb ? 1.f : 0.f;
                    nib |= sb ? (1u << r) : 0u;
                    acc[i][j][r] = 0.f;                 // reset for next t
                }
                int lloc = lw + i*16 + q*4;             // rows l, consecutive 4
                atomicOr(&bits_s[mw + j*16 + n15][lloc >> 5], nib << (lloc & 31));
            }
        __syncthreads();
        if (tid < 128) {
            int m = tid >> 1, wd = tid & 1;
            bits[((size_t)(tb*H_ + h)*L_ + mbase + m)*32 + (lbase >> 5) + wd] = bits_s[m][wd];
        }
        __syncthreads();
    }
}

// ============ K4: outpre = y2 @ spikes (MFMA, B unpacked from bits) ========
__global__ __launch_bounds__(256) void attn_out_mfma(
    const unsigned* __restrict__ y2hm, const unsigned short* __restrict__ y2lo,
    const unsigned* __restrict__ bits, float* __restrict__ outpre) {
    __shared__ unsigned short A_hi[48][72], A_mi[48][72], A_lo[48][72];
    const int tid = threadIdx.x;
    const int t = blockIdx.y >> 4, b = (blockIdx.y >> 3) & 1, h = blockIdx.y & 7;
    const int tb = t*B_ + b;
    const int w = tid >> 6, lane = tid & 63;
    const int q = lane >> 4, n15 = lane & 15;
    const int mb = blockIdx.x*64 + w*16;

    floatx4 acc[3];
#pragma unroll
    for (int i = 0; i < 3; i++) acc[i] = (floatx4){0.f,0.f,0.f,0.f};

    const unsigned* brow = bits + ((size_t)(tb*H_ + h)*L_ + mb + n15)*32;

    for (int lt = 0; lt < L_; lt += 64) {
        for (int s = tid; s < 768; s += 256) {
            int r = s >> 4, c4 = s & 15;
            size_t idx = ((size_t)tb*C_ + h*48 + r)*L_ + lt + c4*4;
            uint4 u = *(const uint4*)(y2hm + idx);
            uint2 ul = *(const uint2*)(y2lo + idx);
            union { unsigned short us[4]; uint2 u2; } hh, mm;
            hh.us[0] = (unsigned short)u.x; hh.us[1] = (unsigned short)u.y;
            hh.us[2] = (unsigned short)u.z; hh.us[3] = (unsigned short)u.w;
            mm.us[0] = (unsigned short)(u.x >> 16); mm.us[1] = (unsigned short)(u.y >> 16);
            mm.us[2] = (unsigned short)(u.z >> 16); mm.us[3] = (unsigned short)(u.w >> 16);
            *(uint2*)&A_hi[r][c4*4] = hh.u2;
            *(uint2*)&A_mi[r][c4*4] = mm.u2;
            *(uint2*)&A_lo[r][c4*4] = ul;
        }
        uint2 bw = *(const uint2*)(brow + (lt >> 5));
        __syncthreads();
#pragma unroll
        for (int kc = 0; kc < 2; kc++) {
            unsigned word = kc ? bw.y : bw.x;
            unsigned byt = (word >> (q*8)) & 0xFFu;     // 8 consecutive l-bits for this lane
            union { unsigned u[4]; short8 v; } bu;
#pragma unroll
            for (int p = 0; p < 4; p++)
                bu.u[p] = (((byt >> (2*p)) & 1u) ? 0x3F80u : 0u)
                        | (((byt >> (2*p+1)) & 1u) ? 0x3F800000u : 0u);
            short8 bfrag = bu.v;
#pragma unroll
            for (int i = 0; i < 3; i++) {
                int ra = i*16 + n15;
                short8 ah = *(short8*)&A_hi[ra][kc*32 + q*8];
                short8 am = *(short8*)&A_mi[ra][kc*32 + q*8];
                short8 al = *(short8*)&A_lo[ra][kc*32 + q*8];
                acc[i] = __builtin_amdgcn_mfma_f32_16x16x32_bf16(ah, bfrag, acc[i], 0,0,0);
                acc[i] = __builtin_amdgcn_mfma_f32_16x16x32_bf16(am, bfrag, acc[i], 0,0,0);
                acc[i] = __builtin_amdgcn_mfma_f32_16x16x32_bf16(al, bfrag, acc[i], 0,0,0);
            }
        }
        __syncthreads();
    }
#pragma unroll
    for (int i = 0; i < 3; i++)
#pragma unroll
        for (int r = 0; r < 4; r++) {
            int d = i*16 + q*4 + r;
            outpre[((size_t)tb*C_ + h*48 + d)*L_ + mb + n15] = acc[i][r];
        }
}

// ============ K6: out = BN2(proj @ outs) + x (MFMA, 96x64 tile) ============
__global__ __launch_bounds__(256) void gemm2_mfma(
    const float* __restrict__ W, const unsigned short* __restrict__ xT,
    const float* __restrict__ g, const float* __restrict__ be,
    const float* __restrict__ mn, const float* __restrict__ vr,
    const float* __restrict__ res, float* __restrict__ out) {
    __shared__ unsigned short A_hi[96][40], A_mi[96][40], A_lo[96][40];
    __shared__ unsigned short B_s[64][40];
    const int tid = threadIdx.x;
    const int tb = blockIdx.y;
    const int mt = blockIdx.x >> 4, lt = blockIdx.x & 15;
    const int l0 = lt * 64;
    const int w = tid >> 6, lane = tid & 63;
    const int q = lane >> 4, n15 = lane & 15;
    const int mw = (w & 1) * 48, lw = (w >> 1) * 32;

    floatx4 acc[3][2];
#pragma unroll
    for (int i = 0; i < 3; i++)
#pragma unroll
        for (int j = 0; j < 2; j++) acc[i][j] = (floatx4){0.f,0.f,0.f,0.f};

    for (int ck = 0; ck < C_; ck += 32) {
        for (int s = tid; s < 768; s += 256) {
            int r = s >> 3, kq = s & 7;
            float4 wv = *(const float4*)(W + (size_t)(mt*96 + r)*C_ + ck + kq*4);
            float ww[4] = {wv.x, wv.y, wv.z, wv.w};
            union { unsigned short us[4]; uint2 u2; } ch, cm, cl;
#pragma unroll
            for (int e = 0; e < 4; e++) {
                unsigned hh, mm, ll; split3(ww[e], hh, mm, ll);
                ch.us[e] = (unsigned short)hh; cm.us[e] = (unsigned short)mm; cl.us[e] = (unsigned short)ll;
            }
            *(uint2*)&A_hi[r][kq*4] = ch.u2;
            *(uint2*)&A_mi[r][kq*4] = cm.u2;
            *(uint2*)&A_lo[r][kq*4] = cl.u2;
        }
        {
            int r = tid >> 2, c4 = tid & 3;             // 256 = 64 rows x 4
            uint4 u = *(const uint4*)(xT + ((size_t)tb*L_ + l0 + r)*C_ + ck + c4*8);
            *(uint4*)&B_s[r][c4*8] = u;
        }
        __syncthreads();
        short8 bb[2];
#pragma unroll
        for (int in = 0; in < 2; in++)
            bb[in] = *(short8*)&B_s[lw + in*16 + n15][q*8];
#pragma unroll
        for (int im = 0; im < 3; im++) {
            short8 ah = *(short8*)&A_hi[mw + im*16 + n15][q*8];
            short8 am = *(short8*)&A_mi[mw + im*16 + n15][q*8];
            short8 al = *(short8*)&A_lo[mw + im*16 + n15][q*8];
#pragma unroll
            for (int in = 0; in < 2; in++) {
                acc[im][in] = __builtin_amdgcn_mfma_f32_16x16x32_bf16(ah, bb[in], acc[im][in], 0,0,0);
                acc[im][in] = __builtin_amdgcn_mfma_f32_16x16x32_bf16(am, bb[in], acc[im][in], 0,0,0);
                acc[im][in] = __builtin_amdgcn_mfma_f32_16x16x32_bf16(al, bb[in], acc[im][in], 0,0,0);
            }
        }
        __syncthreads();
    }
#pragma unroll
    for (int im = 0; im < 3; im++)
#pragma unroll
        for (int r = 0; r < 4; r++) {
            int o = mt*96 + mw + im*16 + q*4 + r;
            float inv = g[o] / sqrtf(vr[o] + 1e-5f);
            float sh = be[o] - mn[o]*inv;
#pragma unroll
            for (int in = 0; in < 2; in++) {
                int l = l0 + lw + in*16 + n15;
                size_t idx = ((size_t)tb*C_ + o)*L_ + l;
                out[idx] = acc[im][in][r]*inv + sh + res[idx];
            }
        }
}

extern "C" void kernel_launch(void* const* d_in, const int* in_sizes, int n_in,
                              void* d_out, int out_size, void* d_ws, size_t ws_size,
                              hipStream_t stream) {
    const float* x   = (const float*)d_in[0];
    const float* W_w = (const float*)d_in[1];
    const float* g1  = (const float*)d_in[2];
    const float* b1  = (const float*)d_in[3];
    const float* m1  = (const float*)d_in[4];
    const float* v1  = (const float*)d_in[5];
    const float* pw  = (const float*)d_in[6];
    const float* g2  = (const float*)d_in[7];
    const float* b2  = (const float*)d_in[8];
    const float* m2  = (const float*)d_in[9];
    const float* v2  = (const float*)d_in[10];

    float* ws = (float*)d_ws;
    unsigned short* xsT  = (unsigned short*)ws;              // 1,572,864 f
    unsigned*       y1hm = (unsigned*)(ws + 1572864);        // 3,145,728 f
    unsigned short* y1lo = (unsigned short*)(ws + 4718592);  // 1,572,864 f
    unsigned*       y2hm = (unsigned*)(ws + 6291456);        // 3,145,728 f
    unsigned short* y2lo = (unsigned short*)(ws + 9437184);  // 1,572,864 f
    unsigned*       bits = (unsigned*)(ws + 11010048);       // 2,097,152 f -> end 13,107,200 f = 52.4 MB
    float*          outpre = (float*)(ws + 1572864);         // alias y1hm (dead after K3)
    unsigned short* outsT  = (unsigned short*)(ws + 4718592);// alias y1lo (dead after K3)
    float* out = (float*)d_out;

    // 1) xs spikes (exact fp32 scan) -> bf16, transposed [tb][l][c]
    scan_transpose<<<dim3(16, 6, B_), 256, 0, stream>>>(x, xsT);
    // 2) y = BN1(W @ xs): MFMA; y1 transposed hi/mid/lo, y2 natural hi/mid/lo
    gemm1_mfma<<<dim3(64, 8), 256, 0, stream>>>(W_w, xsT, g1, b1, m1, v1, y1hm, y1lo, y2hm, y2lo);
    // 3) attn spikes: MFMA + t-scan in regs -> bit-packed [m][l/32]
    attn_spike_mfma<<<dim3(256, 16), 256, 0, stream>>>(y1hm, y1lo, xsT, bits);
    // 4) outpre = y2 @ spikes: MFMA, B unpacked from bits in registers
    attn_out_mfma<<<dim3(16, 64), 256, 0, stream>>>(y2hm, y2lo, bits, outpre);
    // 5) outs spikes -> bf16 transposed
    scan_transpose<<<dim3(16, 6, B_), 256, 0, stream>>>(outpre, outsT);
    // 6) out = BN2(proj @ outs) + x: MFMA
    gemm2_mfma<<<dim3(64, 8), 256, 0, stream>>>(pw, outsT, g2, b2, m2, v2, x, out);
}

// Round 6
// 249.283 us; speedup vs baseline: 1.8893x; 1.0712x over previous
//
#include <hip/hip_runtime.h>

#define T_  4
#define B_  2
#define C_  384
#define L_  1024
#define H_  8
#define C2_ 768
#define S_  (B_*C_*L_)

typedef __attribute__((ext_vector_type(8))) short short8;
typedef __attribute__((ext_vector_type(4))) float floatx4;
typedef __attribute__((ext_vector_type(16))) float floatx16;

__device__ __forceinline__ unsigned bf16_rne(float v) {
    unsigned u = __float_as_uint(v);
    u += 0x7FFFu + ((u >> 16) & 1u);
    return u >> 16;
}
__device__ __forceinline__ float bf16_to_f(unsigned h) { return __uint_as_float(h << 16); }
// v = hi + mid + lo + eps, |eps| <= 2^-27 |v|
__device__ __forceinline__ void split3(float v, unsigned& hi, unsigned& mi, unsigned& lo) {
    hi = bf16_rne(v);
    float r1 = v - bf16_to_f(hi);
    mi = bf16_rne(r1);
    float r2 = r1 - bf16_to_f(mi);
    lo = bf16_rne(r2);
}

// ============ K1/K5: mem_update scan over T + bf16 spike transpose =========
// src fp32 [t][b][C][L]  ->  dstT bf16(0/1) [t][b][L][C]
__global__ __launch_bounds__(256) void scan_transpose(const float* __restrict__ src,
                                                      unsigned short* __restrict__ dstT) {
    __shared__ unsigned short tile[64][72];
    const int tid = threadIdx.x;
    const int l0 = blockIdx.x * 64, c0 = blockIdx.y * 64, b = blockIdx.z;
    const int row = tid >> 2, seg = tid & 3;
    float mem[16], sp[16];
#pragma unroll
    for (int e = 0; e < 16; e++) { mem[e] = 0.f; sp[e] = 0.f; }
    for (int t = 0; t < T_; t++) {
        const size_t base = ((size_t)((t*B_ + b)*C_ + c0 + row))*L_ + l0 + seg*16;
#pragma unroll
        for (int qq = 0; qq < 4; qq++) {
            float4 v = *(const float4*)(src + base + qq*4);
            float vv[4] = {v.x, v.y, v.z, v.w};
            unsigned bs[4];
#pragma unroll
            for (int s = 0; s < 4; s++) {
                int e = qq*4 + s;
                mem[e] = mem[e]*0.25f*(1.f - sp[e]) + vv[s];
                bool sb = mem[e] > 0.5f;
                sp[e] = sb ? 1.f : 0.f;
                bs[s] = sb ? 0x3F80u : 0u;
            }
            *(unsigned*)&tile[row][seg*16 + qq*4]     = bs[0] | (bs[1] << 16);
            *(unsigned*)&tile[row][seg*16 + qq*4 + 2] = bs[2] | (bs[3] << 16);
        }
        __syncthreads();
        {
            const int lr = tid >> 2, cs = tid & 3;
#pragma unroll
            for (int sub = 0; sub < 2; sub++) {
                unsigned wv[4];
#pragma unroll
                for (int p = 0; p < 4; p++) {
                    unsigned e0 = tile[cs*16 + sub*8 + p*2][lr];
                    unsigned e1 = tile[cs*16 + sub*8 + p*2 + 1][lr];
                    wv[p] = e0 | (e1 << 16);
                }
                uint4 o; o.x = wv[0]; o.y = wv[1]; o.z = wv[2]; o.w = wv[3];
                *(uint4*)(dstT + ((size_t)(t*B_ + b)*L_ + l0 + lr)*C_ + c0 + cs*16 + sub*8) = o;
            }
        }
        __syncthreads();
    }
}

// ============ K2: y = BN1(W @ xs) via MFMA, W 3-way split ===================
// out: y1 planes transposed [tb][l][384], y2 planes natural [tb][384][l]
__global__ __launch_bounds__(256) void gemm1_mfma(
    const float* __restrict__ W, const unsigned short* __restrict__ xsT,
    const float* __restrict__ g, const float* __restrict__ be,
    const float* __restrict__ mn, const float* __restrict__ vr,
    unsigned short* __restrict__ y1hi, unsigned short* __restrict__ y1mi,
    unsigned short* __restrict__ y1lo,
    unsigned short* __restrict__ y2hi, unsigned short* __restrict__ y2mi,
    unsigned short* __restrict__ y2lo) {
    __shared__ unsigned short A_hi[96][40], A_mi[96][40], A_lo[96][40];
    __shared__ unsigned short B_s[128][40];
    const int tid = threadIdx.x;
    const int tb = blockIdx.y;
    const int mt = blockIdx.x >> 3, lt = blockIdx.x & 7;
    const int l0 = lt * 128;
    const int w = tid >> 6, lane = tid & 63;
    const int q = lane >> 4, n15 = lane & 15;
    const int mw = (w & 1) * 48, lw = (w >> 1) * 64;

    floatx4 acc[3][4];
#pragma unroll
    for (int i = 0; i < 3; i++)
#pragma unroll
        for (int j = 0; j < 4; j++) acc[i][j] = (floatx4){0.f,0.f,0.f,0.f};

    for (int ck = 0; ck < C_; ck += 32) {
        for (int s = tid; s < 768; s += 256) {
            int r = s >> 3, kq = s & 7;
            float4 wv = *(const float4*)(W + (size_t)(mt*96 + r)*C_ + ck + kq*4);
            float ww[4] = {wv.x, wv.y, wv.z, wv.w};
            union { unsigned short us[4]; uint2 u2; } ch, cm, cl;
#pragma unroll
            for (int e = 0; e < 4; e++) {
                unsigned hh, mm, ll; split3(ww[e], hh, mm, ll);
                ch.us[e] = (unsigned short)hh; cm.us[e] = (unsigned short)mm; cl.us[e] = (unsigned short)ll;
            }
            *(uint2*)&A_hi[r][kq*4] = ch.u2;
            *(uint2*)&A_mi[r][kq*4] = cm.u2;
            *(uint2*)&A_lo[r][kq*4] = cl.u2;
        }
        for (int s = tid; s < 512; s += 256) {
            int r = s >> 2, c4 = s & 3;
            uint4 u = *(const uint4*)(xsT + ((size_t)tb*L_ + l0 + r)*C_ + ck + c4*8);
            *(uint4*)&B_s[r][c4*8] = u;
        }
        __syncthreads();
        short8 bb[4];
#pragma unroll
        for (int in = 0; in < 4; in++)
            bb[in] = *(short8*)&B_s[lw + in*16 + n15][q*8];
#pragma unroll
        for (int im = 0; im < 3; im++) {
            short8 ah = *(short8*)&A_hi[mw + im*16 + n15][q*8];
            short8 am = *(short8*)&A_mi[mw + im*16 + n15][q*8];
            short8 al = *(short8*)&A_lo[mw + im*16 + n15][q*8];
#pragma unroll
            for (int in = 0; in < 4; in++) {
                acc[im][in] = __builtin_amdgcn_mfma_f32_16x16x32_bf16(ah, bb[in], acc[im][in], 0,0,0);
                acc[im][in] = __builtin_amdgcn_mfma_f32_16x16x32_bf16(am, bb[in], acc[im][in], 0,0,0);
                acc[im][in] = __builtin_amdgcn_mfma_f32_16x16x32_bf16(al, bb[in], acc[im][in], 0,0,0);
            }
        }
        __syncthreads();
    }
#pragma unroll
    for (int im = 0; im < 3; im++)
#pragma unroll
        for (int r = 0; r < 4; r++) {
            int og = mw + im*16 + q*4 + r;              // 0..95, wave-uniform half
            int o = mt*96 + og;
            float inv = g[o] / sqrtf(vr[o] + 1e-5f);
            float sh = be[o] - mn[o]*inv;
#pragma unroll
            for (int in = 0; in < 4; in++) {
                int l = l0 + lw + in*16 + n15;
                float v = acc[im][in][r]*inv + sh;
                unsigned hh, mm, ll; split3(v, hh, mm, ll);
                if (og < 48) {
                    size_t idx = ((size_t)tb*L_ + l)*C_ + mt*48 + og;
                    y1hi[idx] = (unsigned short)hh;
                    y1mi[idx] = (unsigned short)mm;
                    y1lo[idx] = (unsigned short)ll;
                } else {
                    size_t idx = ((size_t)tb*C_ + mt*48 + og - 48)*L_ + l;
                    y2hi[idx] = (unsigned short)hh;
                    y2mi[idx] = (unsigned short)mm;
                    y2lo[idx] = (unsigned short)ll;
                }
            }
        }
}

// ============ K3: attn = y1^T @ xr (32x32x16 MFMA, K=48 exact) =============
// t-scan in regs; bits packed [m][l/32]
__global__ __launch_bounds__(256) void attn_spike_mfma(
    const unsigned short* __restrict__ y1hi, const unsigned short* __restrict__ y1mi,
    const unsigned short* __restrict__ y1lo, const unsigned short* __restrict__ xsT,
    unsigned* __restrict__ bits) {
    __shared__ unsigned short A_hi[64][56], A_mi[64][56], A_lo[64][56], B_s[64][56];
    __shared__ unsigned bits_s[64][2];
    const int tid = threadIdx.x;
    const int b = blockIdx.y >> 3, h = blockIdx.y & 7;
    const int lbase = (blockIdx.x >> 4)*64, mbase = (blockIdx.x & 15)*64;
    const int w = tid >> 6, lane = tid & 63;
    const int l31 = lane & 31, half = lane >> 5;
    const int i = w & 1, j = w >> 1;                    // l-subtile, m-subtile

    float mem[16];
#pragma unroll
    for (int r = 0; r < 16; r++) mem[r] = 0.f;

    for (int t = 0; t < T_; t++) {
        const int tb = t*B_ + b;
        const size_t yb = ((size_t)tb*L_ + lbase)*C_ + h*48;
        const size_t xb = ((size_t)tb*L_ + mbase)*C_ + h*48;
        for (int s = tid; s < 512; s += 256) {          // 64 rows x 8 chunks (6 used)
            int r = s >> 3, c = s & 7;
            if (c < 6) {
                size_t ro = (size_t)r*C_ + c*8;
                *(uint4*)&A_hi[r][c*8] = *(const uint4*)(y1hi + yb + ro);
                *(uint4*)&A_mi[r][c*8] = *(const uint4*)(y1mi + yb + ro);
                *(uint4*)&A_lo[r][c*8] = *(const uint4*)(y1lo + yb + ro);
                *(uint4*)&B_s[r][c*8]  = *(const uint4*)(xsT  + xb + ro);
            }
        }
        if (tid < 128) bits_s[tid >> 1][tid & 1] = 0u;
        __syncthreads();

        floatx16 acc = {0.f,0.f,0.f,0.f,0.f,0.f,0.f,0.f,0.f,0.f,0.f,0.f,0.f,0.f,0.f,0.f};
#pragma unroll
        for (int ks = 0; ks < 3; ks++) {
            const int kcol = ks*16 + half*8;
            short8 bb = *(short8*)&B_s[j*32 + l31][kcol];
            short8 ah = *(short8*)&A_hi[i*32 + l31][kcol];
            short8 am = *(short8*)&A_mi[i*32 + l31][kcol];
            short8 al = *(short8*)&A_lo[i*32 + l31][kcol];
            acc = __builtin_amdgcn_mfma_f32_32x32x16_bf16(ah, bb, acc, 0,0,0);
            acc = __builtin_amdgcn_mfma_f32_32x32x16_bf16(am, bb, acc, 0,0,0);
            acc = __builtin_amdgcn_mfma_f32_32x32x16_bf16(al, bb, acc, 0,0,0);
        }

        unsigned word = 0;
#pragma unroll
        for (int r = 0; r < 16; r++) {
            float m = (mem[r] > 0.5f ? 0.f : mem[r]*0.25f) + acc[r];
            mem[r] = m;
            int lloc = (r & 3) + 8*(r >> 2) + 4*half;   // l within 32-row word
            word |= (m > 0.5f) ? (1u << lloc) : 0u;
        }
        atomicOr(&bits_s[j*32 + l31][i], word);
        __syncthreads();
        if (tid < 128) {
            int m = tid >> 1, wd = tid & 1;
            bits[((size_t)(tb*H_ + h)*L_ + mbase + m)*32 + (lbase >> 5) + wd] = bits_s[m][wd];
        }
        __syncthreads();
    }
}

// ============ K4: outpre = y2 @ spikes (16x16x32, B unpacked from bits) ====
__global__ __launch_bounds__(256) void attn_out_mfma(
    const unsigned short* __restrict__ y2hi, const unsigned short* __restrict__ y2mi,
    const unsigned short* __restrict__ y2lo,
    const unsigned* __restrict__ bits, float* __restrict__ outpre) {
    __shared__ unsigned short A_hi[48][72], A_mi[48][72], A_lo[48][72];  // 64 cols used + pad
    const int tid = threadIdx.x;
    const int t = blockIdx.y >> 4, b = (blockIdx.y >> 3) & 1, h = blockIdx.y & 7;
    const int tb = t*B_ + b;
    const int w = tid >> 6, lane = tid & 63;
    const int q = lane >> 4, n15 = lane & 15;
    const int mb = blockIdx.x*64 + w*16;

    floatx4 acc[3];
#pragma unroll
    for (int i = 0; i < 3; i++) acc[i] = (floatx4){0.f,0.f,0.f,0.f};

    const unsigned* brow = bits + ((size_t)(tb*H_ + h)*L_ + mb + n15)*32;
    const size_t y2b = ((size_t)tb*C_ + h*48)*L_;

    for (int lt = 0; lt < L_; lt += 64) {
        for (int s = tid; s < 384; s += 256) {          // 48 rows x 8 chunks of 8
            int r = s >> 3, c = s & 7;
            size_t ro = y2b + (size_t)r*L_ + lt + c*8;
            *(uint4*)&A_hi[r][c*8] = *(const uint4*)(y2hi + ro);
            *(uint4*)&A_mi[r][c*8] = *(const uint4*)(y2mi + ro);
            *(uint4*)&A_lo[r][c*8] = *(const uint4*)(y2lo + ro);
        }
        uint2 bw = *(const uint2*)(brow + (lt >> 5));
        __syncthreads();
#pragma unroll
        for (int kc = 0; kc < 2; kc++) {
            unsigned word = kc ? bw.y : bw.x;
            unsigned byt = (word >> (q*8)) & 0xFFu;     // 8 consecutive l-bits
            union { unsigned u[4]; short8 v; } bu;
#pragma unroll
            for (int p = 0; p < 4; p++)
                bu.u[p] = (((byt >> (2*p)) & 1u) ? 0x3F80u : 0u)
                        | (((byt >> (2*p+1)) & 1u) ? 0x3F800000u : 0u);
            short8 bfrag = bu.v;
#pragma unroll
            for (int i = 0; i < 3; i++) {
                int ra = i*16 + n15;
                short8 ah = *(short8*)&A_hi[ra][kc*32 + q*8];
                short8 am = *(short8*)&A_mi[ra][kc*32 + q*8];
                short8 al = *(short8*)&A_lo[ra][kc*32 + q*8];
                acc[i] = __builtin_amdgcn_mfma_f32_16x16x32_bf16(ah, bfrag, acc[i], 0,0,0);
                acc[i] = __builtin_amdgcn_mfma_f32_16x16x32_bf16(am, bfrag, acc[i], 0,0,0);
                acc[i] = __builtin_amdgcn_mfma_f32_16x16x32_bf16(al, bfrag, acc[i], 0,0,0);
            }
        }
        __syncthreads();
    }
#pragma unroll
    for (int i = 0; i < 3; i++)
#pragma unroll
        for (int r = 0; r < 4; r++) {
            int d = i*16 + q*4 + r;
            outpre[((size_t)tb*C_ + h*48 + d)*L_ + mb + n15] = acc[i][r];
        }
}

// ============ K6: out = BN2(proj @ outs) + x (MFMA, 96x64 tile) ============
__global__ __launch_bounds__(256) void gemm2_mfma(
    const float* __restrict__ W, const unsigned short* __restrict__ xT,
    const float* __restrict__ g, const float* __restrict__ be,
    const float* __restrict__ mn, const float* __restrict__ vr,
    const float* __restrict__ res, float* __restrict__ out) {
    __shared__ unsigned short A_hi[96][40], A_mi[96][40], A_lo[96][40];
    __shared__ unsigned short B_s[64][40];
    const int tid = threadIdx.x;
    const int tb = blockIdx.y;
    const int mt = blockIdx.x >> 4, lt = blockIdx.x & 15;
    const int l0 = lt * 64;
    const int w = tid >> 6, lane = tid & 63;
    const int q = lane >> 4, n15 = lane & 15;
    const int mw = (w & 1) * 48, lw = (w >> 1) * 32;

    floatx4 acc[3][2];
#pragma unroll
    for (int i = 0; i < 3; i++)
#pragma unroll
        for (int j = 0; j < 2; j++) acc[i][j] = (floatx4){0.f,0.f,0.f,0.f};

    for (int ck = 0; ck < C_; ck += 32) {
        for (int s = tid; s < 768; s += 256) {
            int r = s >> 3, kq = s & 7;
            float4 wv = *(const float4*)(W + (size_t)(mt*96 + r)*C_ + ck + kq*4);
            float ww[4] = {wv.x, wv.y, wv.z, wv.w};
            union { unsigned short us[4]; uint2 u2; } ch, cm, cl;
#pragma unroll
            for (int e = 0; e < 4; e++) {
                unsigned hh, mm, ll; split3(ww[e], hh, mm, ll);
                ch.us[e] = (unsigned short)hh; cm.us[e] = (unsigned short)mm; cl.us[e] = (unsigned short)ll;
            }
            *(uint2*)&A_hi[r][kq*4] = ch.u2;
            *(uint2*)&A_mi[r][kq*4] = cm.u2;
            *(uint2*)&A_lo[r][kq*4] = cl.u2;
        }
        {
            int r = tid >> 2, c4 = tid & 3;             // 256 = 64 rows x 4
            uint4 u = *(const uint4*)(xT + ((size_t)tb*L_ + l0 + r)*C_ + ck + c4*8);
            *(uint4*)&B_s[r][c4*8] = u;
        }
        __syncthreads();
        short8 bb[2];
#pragma unroll
        for (int in = 0; in < 2; in++)
            bb[in] = *(short8*)&B_s[lw + in*16 + n15][q*8];
#pragma unroll
        for (int im = 0; im < 3; im++) {
            short8 ah = *(short8*)&A_hi[mw + im*16 + n15][q*8];
            short8 am = *(short8*)&A_mi[mw + im*16 + n15][q*8];
            short8 al = *(short8*)&A_lo[mw + im*16 + n15][q*8];
#pragma unroll
            for (int in = 0; in < 2; in++) {
                acc[im][in] = __builtin_amdgcn_mfma_f32_16x16x32_bf16(ah, bb[in], acc[im][in], 0,0,0);
                acc[im][in] = __builtin_amdgcn_mfma_f32_16x16x32_bf16(am, bb[in], acc[im][in], 0,0,0);
                acc[im][in] = __builtin_amdgcn_mfma_f32_16x16x32_bf16(al, bb[in], acc[im][in], 0,0,0);
            }
        }
        __syncthreads();
    }
#pragma unroll
    for (int im = 0; im < 3; im++)
#pragma unroll
        for (int r = 0; r < 4; r++) {
            int o = mt*96 + mw + im*16 + q*4 + r;
            float inv = g[o] / sqrtf(vr[o] + 1e-5f);
            float sh = be[o] - mn[o]*inv;
#pragma unroll
            for (int in = 0; in < 2; in++) {
                int l = l0 + lw + in*16 + n15;
                size_t idx = ((size_t)tb*C_ + o)*L_ + l;
                out[idx] = acc[im][in][r]*inv + sh + res[idx];
            }
        }
}

extern "C" void kernel_launch(void* const* d_in, const int* in_sizes, int n_in,
                              void* d_out, int out_size, void* d_ws, size_t ws_size,
                              hipStream_t stream) {
    const float* x   = (const float*)d_in[0];
    const float* W_w = (const float*)d_in[1];
    const float* g1  = (const float*)d_in[2];
    const float* b1  = (const float*)d_in[3];
    const float* m1  = (const float*)d_in[4];
    const float* v1  = (const float*)d_in[5];
    const float* pw  = (const float*)d_in[6];
    const float* g2  = (const float*)d_in[7];
    const float* b2  = (const float*)d_in[8];
    const float* m2  = (const float*)d_in[9];
    const float* v2  = (const float*)d_in[10];

    float* ws = (float*)d_ws;
    unsigned short* xsT  = (unsigned short*)ws;               // 1,572,864 f
    unsigned short* y1hi = (unsigned short*)(ws + 1572864);   // 1,572,864 f each
    unsigned short* y1mi = (unsigned short*)(ws + 3145728);
    unsigned short* y1lo = (unsigned short*)(ws + 4718592);
    unsigned short* y2hi = (unsigned short*)(ws + 6291456);
    unsigned short* y2mi = (unsigned short*)(ws + 7864320);
    unsigned short* y2lo = (unsigned short*)(ws + 9437184);
    unsigned*       bits = (unsigned*)(ws + 11010048);        // 2,097,152 words -> 52.4 MB total
    float*          outpre = (float*)(ws + 1572864);          // alias y1hi+y1mi (dead after K3)
    unsigned short* outsT  = (unsigned short*)(ws + 4718592); // alias y1lo (dead after K3)
    float* out = (float*)d_out;

    // 1) xs spikes (exact fp32 scan) -> bf16, transposed [tb][l][c]
    scan_transpose<<<dim3(16, 6, B_), 256, 0, stream>>>(x, xsT);
    // 2) y = BN1(W @ xs): MFMA; y1 planes transposed, y2 planes natural
    gemm1_mfma<<<dim3(64, 8), 256, 0, stream>>>(W_w, xsT, g1, b1, m1, v1,
                                                y1hi, y1mi, y1lo, y2hi, y2mi, y2lo);
    // 3) attn spikes: 32x32x16 MFMA (K=48 exact) -> bit-packed [m][l/32]
    attn_spike_mfma<<<dim3(256, 16), 256, 0, stream>>>(y1hi, y1mi, y1lo, xsT, bits);
    // 4) outpre = y2 @ spikes: MFMA, B unpacked from bits in registers
    attn_out_mfma<<<dim3(16, 64), 256, 0, stream>>>(y2hi, y2mi, y2lo, bits, outpre);
    // 5) outs spikes -> bf16 transposed
    scan_transpose<<<dim3(16, 6, B_), 256, 0, stream>>>(outpre, outsT);
    // 6) out = BN2(proj @ outs) + x: MFMA
    gemm2_mfma<<<dim3(64, 8), 256, 0, stream>>>(pw, outsT, g2, b2, m2, v2, x, out);
}

// Round 7
// 232.083 us; speedup vs baseline: 2.0293x; 1.0741x over previous
//
#include <hip/hip_runtime.h>

#define T_  4
#define B_  2
#define C_  384
#define L_  1024
#define H_  8
#define C2_ 768
#define S_  (B_*C_*L_)

typedef __attribute__((ext_vector_type(8))) short short8;
typedef __attribute__((ext_vector_type(4))) float floatx4;
typedef __attribute__((ext_vector_type(16))) float floatx16;

__device__ __forceinline__ unsigned bf16_rne(float v) {
    unsigned u = __float_as_uint(v);
    u += 0x7FFFu + ((u >> 16) & 1u);
    return u >> 16;
}
__device__ __forceinline__ float bf16_to_f(unsigned h) { return __uint_as_float(h << 16); }
__device__ __forceinline__ void split3(float v, unsigned& hi, unsigned& mi, unsigned& lo) {
    hi = bf16_rne(v);
    float r1 = v - bf16_to_f(hi);
    mi = bf16_rne(r1);
    float r2 = r1 - bf16_to_f(mi);
    lo = bf16_rne(r2);
}

// ============ K0: split fp32 weights into 3 bf16 planes (run once/launch) ==
__global__ __launch_bounds__(256) void split_w(const float* __restrict__ W, int n4,
                                               unsigned short* __restrict__ hi,
                                               unsigned short* __restrict__ mi,
                                               unsigned short* __restrict__ lo) {
    int i = blockIdx.x * 256 + threadIdx.x;
    if (i >= n4) return;
    float4 v = ((const float4*)W)[i];
    float vv[4] = {v.x, v.y, v.z, v.w};
    union { unsigned short us[4]; uint2 u2; } h, m, l;
#pragma unroll
    for (int e = 0; e < 4; e++) {
        unsigned hh, mm, ll; split3(vv[e], hh, mm, ll);
        h.us[e] = (unsigned short)hh; m.us[e] = (unsigned short)mm; l.us[e] = (unsigned short)ll;
    }
    ((uint2*)hi)[i] = h.u2; ((uint2*)mi)[i] = m.u2; ((uint2*)lo)[i] = l.u2;
}

// ============ K1/K5: mem_update scan over T + bf16 spike transpose =========
// src fp32 [t][b][C][L]  ->  dstT bf16(0/1) [t][b][L][C]
__global__ __launch_bounds__(256) void scan_transpose(const float* __restrict__ src,
                                                      unsigned short* __restrict__ dstT) {
    __shared__ unsigned short tile[64][72];
    const int tid = threadIdx.x;
    const int l0 = blockIdx.x * 64, c0 = blockIdx.y * 64, b = blockIdx.z;
    const int row = tid >> 2, seg = tid & 3;
    float mem[16], sp[16];
#pragma unroll
    for (int e = 0; e < 16; e++) { mem[e] = 0.f; sp[e] = 0.f; }
    for (int t = 0; t < T_; t++) {
        const size_t base = ((size_t)((t*B_ + b)*C_ + c0 + row))*L_ + l0 + seg*16;
#pragma unroll
        for (int qq = 0; qq < 4; qq++) {
            float4 v = *(const float4*)(src + base + qq*4);
            float vv[4] = {v.x, v.y, v.z, v.w};
            unsigned bs[4];
#pragma unroll
            for (int s = 0; s < 4; s++) {
                int e = qq*4 + s;
                mem[e] = mem[e]*0.25f*(1.f - sp[e]) + vv[s];
                bool sb = mem[e] > 0.5f;
                sp[e] = sb ? 1.f : 0.f;
                bs[s] = sb ? 0x3F80u : 0u;
            }
            *(unsigned*)&tile[row][seg*16 + qq*4]     = bs[0] | (bs[1] << 16);
            *(unsigned*)&tile[row][seg*16 + qq*4 + 2] = bs[2] | (bs[3] << 16);
        }
        __syncthreads();
        {
            const int lr = tid >> 2, cs = tid & 3;
#pragma unroll
            for (int sub = 0; sub < 2; sub++) {
                unsigned wv[4];
#pragma unroll
                for (int p = 0; p < 4; p++) {
                    unsigned e0 = tile[cs*16 + sub*8 + p*2][lr];
                    unsigned e1 = tile[cs*16 + sub*8 + p*2 + 1][lr];
                    wv[p] = e0 | (e1 << 16);
                }
                uint4 o; o.x = wv[0]; o.y = wv[1]; o.z = wv[2]; o.w = wv[3];
                *(uint4*)(dstT + ((size_t)(t*B_ + b)*L_ + l0 + lr)*C_ + c0 + cs*16 + sub*8) = o;
            }
        }
        __syncthreads();
    }
}

// ============ K2: y = BN1(W @ xs) via MFMA ================================
// y1 planes compact [tb][h][l][48]; y2 planes natural [tb][c][l]
// Epilogue: LDS transpose -> coalesced uint4 stores (block-exclusive lines)
__global__ __launch_bounds__(256) void gemm1_mfma(
    const unsigned short* __restrict__ whi, const unsigned short* __restrict__ wmi,
    const unsigned short* __restrict__ wlo, const unsigned short* __restrict__ xsT,
    const float* __restrict__ g, const float* __restrict__ be,
    const float* __restrict__ mn, const float* __restrict__ vr,
    unsigned short* __restrict__ y1hi, unsigned short* __restrict__ y1mi,
    unsigned short* __restrict__ y1lo,
    unsigned short* __restrict__ y2hi, unsigned short* __restrict__ y2mi,
    unsigned short* __restrict__ y2lo) {
    __shared__ unsigned short A_hi[96][40], A_mi[96][40], A_lo[96][40];
    __shared__ unsigned short B_s[128][40];
    __shared__ unsigned short epi1[128*56];   // y1: [l(128)][48 c + pad]
    __shared__ unsigned short epi2[48*136];   // y2: [c(48)][128 l + pad]
    const int tid = threadIdx.x;
    const int tb = blockIdx.y;
    const int mt = blockIdx.x >> 3, lt = blockIdx.x & 7;
    const int l0 = lt * 128;
    const int w = tid >> 6, lane = tid & 63;
    const int q = lane >> 4, n15 = lane & 15;
    const int mw = (w & 1) * 48, lw = (w >> 1) * 64;

    floatx4 acc[3][4];
#pragma unroll
    for (int i = 0; i < 3; i++)
#pragma unroll
        for (int j = 0; j < 4; j++) acc[i][j] = (floatx4){0.f,0.f,0.f,0.f};

    for (int ck = 0; ck < C_; ck += 32) {
#pragma unroll
        for (int p = 0; p < 3; p++) {
            const unsigned short* wp = p == 0 ? whi : p == 1 ? wmi : wlo;
            unsigned short (*ap)[40] = p == 0 ? A_hi : p == 1 ? A_mi : A_lo;
            for (int s = tid; s < 384; s += 256) {
                int r = s >> 2, c = s & 3;
                *(uint4*)&ap[r][c*8] = *(const uint4*)(wp + (size_t)(mt*96 + r)*C_ + ck + c*8);
            }
        }
        for (int s = tid; s < 512; s += 256) {
            int r = s >> 2, c4 = s & 3;
            *(uint4*)&B_s[r][c4*8] = *(const uint4*)(xsT + ((size_t)tb*L_ + l0 + r)*C_ + ck + c4*8);
        }
        __syncthreads();
        short8 bb[4];
#pragma unroll
        for (int in = 0; in < 4; in++)
            bb[in] = *(short8*)&B_s[lw + in*16 + n15][q*8];
#pragma unroll
        for (int im = 0; im < 3; im++) {
            short8 ah = *(short8*)&A_hi[mw + im*16 + n15][q*8];
            short8 am = *(short8*)&A_mi[mw + im*16 + n15][q*8];
            short8 al = *(short8*)&A_lo[mw + im*16 + n15][q*8];
#pragma unroll
            for (int in = 0; in < 4; in++) {
                acc[im][in] = __builtin_amdgcn_mfma_f32_16x16x32_bf16(ah, bb[in], acc[im][in], 0,0,0);
                acc[im][in] = __builtin_amdgcn_mfma_f32_16x16x32_bf16(am, bb[in], acc[im][in], 0,0,0);
                acc[im][in] = __builtin_amdgcn_mfma_f32_16x16x32_bf16(al, bb[in], acc[im][in], 0,0,0);
            }
        }
        __syncthreads();
    }

    // ---- epilogue: BN in place, then 3 planes via LDS transpose ----
#pragma unroll
    for (int im = 0; im < 3; im++)
#pragma unroll
        for (int r = 0; r < 4; r++) {
            int o = mt*96 + mw + im*16 + q*4 + r;
            float inv = g[o] / sqrtf(vr[o] + 1e-5f);
            float sh = be[o] - mn[o]*inv;
#pragma unroll
            for (int in = 0; in < 4; in++)
                acc[im][in][r] = acc[im][in][r]*inv + sh;
        }
    const bool isY1 = ((w & 1) == 0);
#pragma unroll
    for (int p = 0; p < 3; p++) {
        if (isY1) {
#pragma unroll
            for (int im = 0; im < 3; im++)
#pragma unroll
                for (int in = 0; in < 4; in++) {
                    union { unsigned short us[4]; uint2 u2; } pk;
#pragma unroll
                    for (int r = 0; r < 4; r++) {
                        unsigned hh = bf16_rne(acc[im][in][r]);
                        pk.us[r] = (unsigned short)hh;
                        acc[im][in][r] -= bf16_to_f(hh);
                    }
                    *(uint2*)&epi1[(lw + in*16 + n15)*56 + im*16 + q*4] = pk.u2;
                }
        } else {
#pragma unroll
            for (int im = 0; im < 3; im++)
#pragma unroll
                for (int in = 0; in < 4; in++)
#pragma unroll
                    for (int r = 0; r < 4; r++) {
                        unsigned hh = bf16_rne(acc[im][in][r]);
                        epi2[(im*16 + q*4 + r)*136 + lw + in*16 + n15] = (unsigned short)hh;
                        acc[im][in][r] -= bf16_to_f(hh);
                    }
        }
        __syncthreads();
        unsigned short* y1p = p == 0 ? y1hi : p == 1 ? y1mi : y1lo;
        unsigned short* y2p = p == 0 ? y2hi : p == 1 ? y2mi : y2lo;
#pragma unroll
        for (int k2 = 0; k2 < 3; k2++) {
            int s = tid + k2*256;                      // s < 768
            int r1 = s / 6, c8 = s % 6;
            *(uint4*)(y1p + (((size_t)tb*H_ + mt)*L_ + l0 + r1)*48 + c8*8) =
                *(uint4*)&epi1[r1*56 + c8*8];
            int cr = s >> 4, lq = s & 15;
            *(uint4*)(y2p + ((size_t)tb*C_ + mt*48 + cr)*L_ + l0 + lq*8) =
                *(uint4*)&epi2[cr*136 + lq*8];
        }
        __syncthreads();
    }
}

// ============ K3: attn = y1^T @ xr (32x32x16 MFMA, K=48 exact) =============
__global__ __launch_bounds__(256) void attn_spike_mfma(
    const unsigned short* __restrict__ y1hi, const unsigned short* __restrict__ y1mi,
    const unsigned short* __restrict__ y1lo, const unsigned short* __restrict__ xsT,
    unsigned* __restrict__ bits) {
    __shared__ unsigned short A_hi[64][56], A_mi[64][56], A_lo[64][56], B_s[64][56];
    __shared__ unsigned bits_s[64][2];
    const int tid = threadIdx.x;
    const int b = blockIdx.y >> 3, h = blockIdx.y & 7;
    const int lbase = (blockIdx.x >> 4)*64, mbase = (blockIdx.x & 15)*64;
    const int w = tid >> 6, lane = tid & 63;
    const int l31 = lane & 31, half = lane >> 5;
    const int i = w & 1, j = w >> 1;

    float mem[16];
#pragma unroll
    for (int r = 0; r < 16; r++) mem[r] = 0.f;

    for (int t = 0; t < T_; t++) {
        const int tb = t*B_ + b;
        const size_t yb = (((size_t)tb*H_ + h)*L_ + lbase)*48;
        const size_t xb = ((size_t)tb*L_ + mbase)*C_ + h*48;
        for (int s = tid; s < 384; s += 256) {
            int r = s / 6, c = s % 6;
            size_t ro = yb + (size_t)r*48 + c*8;
            *(uint4*)&A_hi[r][c*8] = *(const uint4*)(y1hi + ro);
            *(uint4*)&A_mi[r][c*8] = *(const uint4*)(y1mi + ro);
            *(uint4*)&A_lo[r][c*8] = *(const uint4*)(y1lo + ro);
            *(uint4*)&B_s[r][c*8]  = *(const uint4*)(xsT + xb + (size_t)r*C_ + c*8);
        }
        if (tid < 128) bits_s[tid >> 1][tid & 1] = 0u;
        __syncthreads();

        floatx16 acc = {0.f,0.f,0.f,0.f,0.f,0.f,0.f,0.f,0.f,0.f,0.f,0.f,0.f,0.f,0.f,0.f};
#pragma unroll
        for (int ks = 0; ks < 3; ks++) {
            const int kcol = ks*16 + half*8;
            short8 bb = *(short8*)&B_s[j*32 + l31][kcol];
            short8 ah = *(short8*)&A_hi[i*32 + l31][kcol];
            short8 am = *(short8*)&A_mi[i*32 + l31][kcol];
            short8 al = *(short8*)&A_lo[i*32 + l31][kcol];
            acc = __builtin_amdgcn_mfma_f32_32x32x16_bf16(ah, bb, acc, 0,0,0);
            acc = __builtin_amdgcn_mfma_f32_32x32x16_bf16(am, bb, acc, 0,0,0);
            acc = __builtin_amdgcn_mfma_f32_32x32x16_bf16(al, bb, acc, 0,0,0);
        }

        unsigned word = 0;
#pragma unroll
        for (int r = 0; r < 16; r++) {
            float m = (mem[r] > 0.5f ? 0.f : mem[r]*0.25f) + acc[r];
            mem[r] = m;
            int lloc = (r & 3) + 8*(r >> 2) + 4*half;
            word |= (m > 0.5f) ? (1u << lloc) : 0u;
        }
        atomicOr(&bits_s[j*32 + l31][i], word);
        __syncthreads();
        if (tid < 128) {
            int m = tid >> 1, wd = tid & 1;
            bits[((size_t)(tb*H_ + h)*L_ + mbase + m)*32 + (lbase >> 5) + wd] = bits_s[m][wd];
        }
        __syncthreads();
    }
}

// ============ K4: outpre = y2 @ spikes (16x16x32, B unpacked from bits) ====
__global__ __launch_bounds__(256) void attn_out_mfma(
    const unsigned short* __restrict__ y2hi, const unsigned short* __restrict__ y2mi,
    const unsigned short* __restrict__ y2lo,
    const unsigned* __restrict__ bits, float* __restrict__ outpre) {
    __shared__ unsigned short A_hi[48][72], A_mi[48][72], A_lo[48][72];
    const int tid = threadIdx.x;
    const int t = blockIdx.y >> 4, b = (blockIdx.y >> 3) & 1, h = blockIdx.y & 7;
    const int tb = t*B_ + b;
    const int w = tid >> 6, lane = tid & 63;
    const int q = lane >> 4, n15 = lane & 15;
    const int mb = blockIdx.x*64 + w*16;

    floatx4 acc[3];
#pragma unroll
    for (int i = 0; i < 3; i++) acc[i] = (floatx4){0.f,0.f,0.f,0.f};

    const unsigned* brow = bits + ((size_t)(tb*H_ + h)*L_ + mb + n15)*32;
    const size_t y2b = ((size_t)tb*C_ + h*48)*L_;

    for (int lt = 0; lt < L_; lt += 64) {
        for (int s = tid; s < 384; s += 256) {
            int r = s >> 3, c = s & 7;
            size_t ro = y2b + (size_t)r*L_ + lt + c*8;
            *(uint4*)&A_hi[r][c*8] = *(const uint4*)(y2hi + ro);
            *(uint4*)&A_mi[r][c*8] = *(const uint4*)(y2mi + ro);
            *(uint4*)&A_lo[r][c*8] = *(const uint4*)(y2lo + ro);
        }
        uint2 bw = *(const uint2*)(brow + (lt >> 5));
        __syncthreads();
#pragma unroll
        for (int kc = 0; kc < 2; kc++) {
            unsigned word = kc ? bw.y : bw.x;
            unsigned byt = (word >> (q*8)) & 0xFFu;
            union { unsigned u[4]; short8 v; } bu;
#pragma unroll
            for (int p = 0; p < 4; p++)
                bu.u[p] = (((byt >> (2*p)) & 1u) ? 0x3F80u : 0u)
                        | (((byt >> (2*p+1)) & 1u) ? 0x3F800000u : 0u);
            short8 bfrag = bu.v;
#pragma unroll
            for (int i = 0; i < 3; i++) {
                int ra = i*16 + n15;
                short8 ah = *(short8*)&A_hi[ra][kc*32 + q*8];
                short8 am = *(short8*)&A_mi[ra][kc*32 + q*8];
                short8 al = *(short8*)&A_lo[ra][kc*32 + q*8];
                acc[i] = __builtin_amdgcn_mfma_f32_16x16x32_bf16(ah, bfrag, acc[i], 0,0,0);
                acc[i] = __builtin_amdgcn_mfma_f32_16x16x32_bf16(am, bfrag, acc[i], 0,0,0);
                acc[i] = __builtin_amdgcn_mfma_f32_16x16x32_bf16(al, bfrag, acc[i], 0,0,0);
            }
        }
        __syncthreads();
    }
#pragma unroll
    for (int i = 0; i < 3; i++)
#pragma unroll
        for (int r = 0; r < 4; r++) {
            int d = i*16 + q*4 + r;
            outpre[((size_t)tb*C_ + h*48 + d)*L_ + mb + n15] = acc[i][r];
        }
}

// ============ K6: out = BN2(proj @ outs) + x (MFMA, 96x64 tile) ============
__global__ __launch_bounds__(256) void gemm2_mfma(
    const unsigned short* __restrict__ whi, const unsigned short* __restrict__ wmi,
    const unsigned short* __restrict__ wlo, const unsigned short* __restrict__ xT,
    const float* __restrict__ g, const float* __restrict__ be,
    const float* __restrict__ mn, const float* __restrict__ vr,
    const float* __restrict__ res, float* __restrict__ out) {
    __shared__ unsigned short A_hi[96][40], A_mi[96][40], A_lo[96][40];
    __shared__ unsigned short B_s[64][40];
    const int tid = threadIdx.x;
    const int tb = blockIdx.y;
    const int mt = blockIdx.x >> 4, lt = blockIdx.x & 15;
    const int l0 = lt * 64;
    const int w = tid >> 6, lane = tid & 63;
    const int q = lane >> 4, n15 = lane & 15;
    const int mw = (w & 1) * 48, lw = (w >> 1) * 32;

    floatx4 acc[3][2];
#pragma unroll
    for (int i = 0; i < 3; i++)
#pragma unroll
        for (int j = 0; j < 2; j++) acc[i][j] = (floatx4){0.f,0.f,0.f,0.f};

    for (int ck = 0; ck < C_; ck += 32) {
#pragma unroll
        for (int p = 0; p < 3; p++) {
            const unsigned short* wp = p == 0 ? whi : p == 1 ? wmi : wlo;
            unsigned short (*ap)[40] = p == 0 ? A_hi : p == 1 ? A_mi : A_lo;
            for (int s = tid; s < 384; s += 256) {
                int r = s >> 2, c = s & 3;
                *(uint4*)&ap[r][c*8] = *(const uint4*)(wp + (size_t)(mt*96 + r)*C_ + ck + c*8);
            }
        }
        {
            int r = tid >> 2, c4 = tid & 3;
            *(uint4*)&B_s[r][c4*8] = *(const uint4*)(xT + ((size_t)tb*L_ + l0 + r)*C_ + ck + c4*8);
        }
        __syncthreads();
        short8 bb[2];
#pragma unroll
        for (int in = 0; in < 2; in++)
            bb[in] = *(short8*)&B_s[lw + in*16 + n15][q*8];
#pragma unroll
        for (int im = 0; im < 3; im++) {
            short8 ah = *(short8*)&A_hi[mw + im*16 + n15][q*8];
            short8 am = *(short8*)&A_mi[mw + im*16 + n15][q*8];
            short8 al = *(short8*)&A_lo[mw + im*16 + n15][q*8];
#pragma unroll
            for (int in = 0; in < 2; in++) {
                acc[im][in] = __builtin_amdgcn_mfma_f32_16x16x32_bf16(ah, bb[in], acc[im][in], 0,0,0);
                acc[im][in] = __builtin_amdgcn_mfma_f32_16x16x32_bf16(am, bb[in], acc[im][in], 0,0,0);
                acc[im][in] = __builtin_amdgcn_mfma_f32_16x16x32_bf16(al, bb[in], acc[im][in], 0,0,0);
            }
        }
        __syncthreads();
    }
#pragma unroll
    for (int im = 0; im < 3; im++)
#pragma unroll
        for (int r = 0; r < 4; r++) {
            int o = mt*96 + mw + im*16 + q*4 + r;
            float inv = g[o] / sqrtf(vr[o] + 1e-5f);
            float sh = be[o] - mn[o]*inv;
#pragma unroll
            for (int in = 0; in < 2; in++) {
                int l = l0 + lw + in*16 + n15;
                size_t idx = ((size_t)tb*C_ + o)*L_ + l;
                out[idx] = acc[im][in][r]*inv + sh + res[idx];
            }
        }
}

extern "C" void kernel_launch(void* const* d_in, const int* in_sizes, int n_in,
                              void* d_out, int out_size, void* d_ws, size_t ws_size,
                              hipStream_t stream) {
    const float* x   = (const float*)d_in[0];
    const float* W_w = (const float*)d_in[1];
    const float* g1  = (const float*)d_in[2];
    const float* b1  = (const float*)d_in[3];
    const float* m1  = (const float*)d_in[4];
    const float* v1  = (const float*)d_in[5];
    const float* pw  = (const float*)d_in[6];
    const float* g2  = (const float*)d_in[7];
    const float* b2  = (const float*)d_in[8];
    const float* m2  = (const float*)d_in[9];
    const float* v2  = (const float*)d_in[10];

    float* ws = (float*)d_ws;
    unsigned short* xsT  = (unsigned short*)ws;               // 1,572,864 f
    unsigned short* y1hi = (unsigned short*)(ws + 1572864);   // 1,572,864 f each
    unsigned short* y1mi = (unsigned short*)(ws + 3145728);
    unsigned short* y1lo = (unsigned short*)(ws + 4718592);
    unsigned short* y2hi = (unsigned short*)(ws + 6291456);
    unsigned short* y2mi = (unsigned short*)(ws + 7864320);
    unsigned short* y2lo = (unsigned short*)(ws + 9437184);
    unsigned*       bits = (unsigned*)(ws + 11010048);        // ends 13,107,200 f
    unsigned short* wspl[3]  = {(unsigned short*)(ws + 13107200),
                                (unsigned short*)(ws + 13254656),
                                (unsigned short*)(ws + 13402112)};
    unsigned short* pwspl[3] = {(unsigned short*)(ws + 13549568),
                                (unsigned short*)(ws + 13623296),
                                (unsigned short*)(ws + 13697024)};  // ends 13,770,752 f = 55.1 MB
    float*          outpre = (float*)(ws + 1572864);          // alias y1hi+y1mi (dead after K3)
    unsigned short* outsT  = (unsigned short*)(ws + 4718592); // alias y1lo (dead after K3)
    float* out = (float*)d_out;

    // 0) split weights into bf16 planes (once per launch)
    split_w<<<dim3(288), 256, 0, stream>>>(W_w, C2_*C_/4, wspl[0], wspl[1], wspl[2]);
    split_w<<<dim3(144), 256, 0, stream>>>(pw,  C_*C_/4, pwspl[0], pwspl[1], pwspl[2]);
    // 1) xs spikes (exact fp32 scan) -> bf16, transposed [tb][l][c]
    scan_transpose<<<dim3(16, 6, B_), 256, 0, stream>>>(x, xsT);
    // 2) y = BN1(W @ xs): y1 compact [tb][h][l][48], y2 natural [tb][c][l]
    gemm1_mfma<<<dim3(64, 8), 256, 0, stream>>>(wspl[0], wspl[1], wspl[2], xsT,
                                                g1, b1, m1, v1,
                                                y1hi, y1mi, y1lo, y2hi, y2mi, y2lo);
    // 3) attn spikes: 32x32x16 MFMA (K=48 exact) -> bit-packed [m][l/32]
    attn_spike_mfma<<<dim3(256, 16), 256, 0, stream>>>(y1hi, y1mi, y1lo, xsT, bits);
    // 4) outpre = y2 @ spikes: MFMA, B unpacked from bits in registers
    attn_out_mfma<<<dim3(16, 64), 256, 0, stream>>>(y2hi, y2mi, y2lo, bits, outpre);
    // 5) outs spikes -> bf16 transposed
    scan_transpose<<<dim3(16, 6, B_), 256, 0, stream>>>(outpre, outsT);
    // 6) out = BN2(proj @ outs) + x
    gemm2_mfma<<<dim3(64, 8), 256, 0, stream>>>(pwspl[0], pwspl[1], pwspl[2], outsT,
                                                g2, b2, m2, v2, x, out);
}

// Round 8
// 223.643 us; speedup vs baseline: 2.1059x; 1.0377x over previous
//
#include <hip/hip_runtime.h>

#define T_  4
#define B_  2
#define C_  384
#define L_  1024
#define H_  8
#define C2_ 768
#define S_  (B_*C_*L_)

typedef __attribute__((ext_vector_type(8))) short short8;
typedef __attribute__((ext_vector_type(4))) float floatx4;
typedef __attribute__((ext_vector_type(16))) float floatx16;

__device__ __forceinline__ unsigned bf16_rne(float v) {
    unsigned u = __float_as_uint(v);
    u += 0x7FFFu + ((u >> 16) & 1u);
    return u >> 16;
}
__device__ __forceinline__ float bf16_to_f(unsigned h) { return __uint_as_float(h << 16); }
__device__ __forceinline__ void split3(float v, unsigned& hi, unsigned& mi, unsigned& lo) {
    hi = bf16_rne(v);
    float r1 = v - bf16_to_f(hi);
    mi = bf16_rne(r1);
    float r2 = r1 - bf16_to_f(mi);
    lo = bf16_rne(r2);
}

// ============ K0: split fp32 weights into 3 bf16 planes (run once/launch) ==
__global__ __launch_bounds__(256) void split_w(const float* __restrict__ W, int n4,
                                               unsigned short* __restrict__ hi,
                                               unsigned short* __restrict__ mi,
                                               unsigned short* __restrict__ lo) {
    int i = blockIdx.x * 256 + threadIdx.x;
    if (i >= n4) return;
    float4 v = ((const float4*)W)[i];
    float vv[4] = {v.x, v.y, v.z, v.w};
    union { unsigned short us[4]; uint2 u2; } h, m, l;
#pragma unroll
    for (int e = 0; e < 4; e++) {
        unsigned hh, mm, ll; split3(vv[e], hh, mm, ll);
        h.us[e] = (unsigned short)hh; m.us[e] = (unsigned short)mm; l.us[e] = (unsigned short)ll;
    }
    ((uint2*)hi)[i] = h.u2; ((uint2*)mi)[i] = m.u2; ((uint2*)lo)[i] = l.u2;
}

// ============ K1/K5: mem_update scan over T + bf16 spike transpose =========
// src fp32 [t][b][C][L]  ->  dstT bf16(0/1) [t][b][L][C]
__global__ __launch_bounds__(256) void scan_transpose(const float* __restrict__ src,
                                                      unsigned short* __restrict__ dstT) {
    __shared__ unsigned short tile[64][72];
    const int tid = threadIdx.x;
    const int l0 = blockIdx.x * 64, c0 = blockIdx.y * 64, b = blockIdx.z;
    const int row = tid >> 2, seg = tid & 3;
    float mem[16], sp[16];
#pragma unroll
    for (int e = 0; e < 16; e++) { mem[e] = 0.f; sp[e] = 0.f; }
    for (int t = 0; t < T_; t++) {
        const size_t base = ((size_t)((t*B_ + b)*C_ + c0 + row))*L_ + l0 + seg*16;
#pragma unroll
        for (int qq = 0; qq < 4; qq++) {
            float4 v = *(const float4*)(src + base + qq*4);
            float vv[4] = {v.x, v.y, v.z, v.w};
            unsigned bs[4];
#pragma unroll
            for (int s = 0; s < 4; s++) {
                int e = qq*4 + s;
                mem[e] = mem[e]*0.25f*(1.f - sp[e]) + vv[s];
                bool sb = mem[e] > 0.5f;
                sp[e] = sb ? 1.f : 0.f;
                bs[s] = sb ? 0x3F80u : 0u;
            }
            *(unsigned*)&tile[row][seg*16 + qq*4]     = bs[0] | (bs[1] << 16);
            *(unsigned*)&tile[row][seg*16 + qq*4 + 2] = bs[2] | (bs[3] << 16);
        }
        __syncthreads();
        {
            const int lr = tid >> 2, cs = tid & 3;
#pragma unroll
            for (int sub = 0; sub < 2; sub++) {
                unsigned wv[4];
#pragma unroll
                for (int p = 0; p < 4; p++) {
                    unsigned e0 = tile[cs*16 + sub*8 + p*2][lr];
                    unsigned e1 = tile[cs*16 + sub*8 + p*2 + 1][lr];
                    wv[p] = e0 | (e1 << 16);
                }
                uint4 o; o.x = wv[0]; o.y = wv[1]; o.z = wv[2]; o.w = wv[3];
                *(uint4*)(dstT + ((size_t)(t*B_ + b)*L_ + l0 + lr)*C_ + c0 + cs*16 + sub*8) = o;
            }
        }
        __syncthreads();
    }
}

// ============ K2: y = BN1(W @ xs) via MFMA ================================
// y1 planes compact [tb][h][l][48]; y2 planes natural [tb][c][l]
__global__ __launch_bounds__(256) void gemm1_mfma(
    const unsigned short* __restrict__ whi, const unsigned short* __restrict__ wmi,
    const unsigned short* __restrict__ wlo, const unsigned short* __restrict__ xsT,
    const float* __restrict__ g, const float* __restrict__ be,
    const float* __restrict__ mn, const float* __restrict__ vr,
    unsigned short* __restrict__ y1hi, unsigned short* __restrict__ y1mi,
    unsigned short* __restrict__ y1lo,
    unsigned short* __restrict__ y2hi, unsigned short* __restrict__ y2mi,
    unsigned short* __restrict__ y2lo) {
    __shared__ unsigned short A_hi[96][40], A_mi[96][40], A_lo[96][40];
    __shared__ unsigned short B_s[128][40];
    __shared__ unsigned short epi1[128*56];   // y1: [l(128)][48 c + pad]
    __shared__ unsigned short epi2[48*136];   // y2: [c(48)][128 l + pad]
    const int tid = threadIdx.x;
    const int tb = blockIdx.y;
    const int mt = blockIdx.x >> 3, lt = blockIdx.x & 7;
    const int l0 = lt * 128;
    const int w = tid >> 6, lane = tid & 63;
    const int q = lane >> 4, n15 = lane & 15;
    const int mw = (w & 1) * 48, lw = (w >> 1) * 64;

    floatx4 acc[3][4];
#pragma unroll
    for (int i = 0; i < 3; i++)
#pragma unroll
        for (int j = 0; j < 4; j++) acc[i][j] = (floatx4){0.f,0.f,0.f,0.f};

    for (int ck = 0; ck < C_; ck += 32) {
#pragma unroll
        for (int p = 0; p < 3; p++) {
            const unsigned short* wp = p == 0 ? whi : p == 1 ? wmi : wlo;
            unsigned short (*ap)[40] = p == 0 ? A_hi : p == 1 ? A_mi : A_lo;
            for (int s = tid; s < 384; s += 256) {
                int r = s >> 2, c = s & 3;
                *(uint4*)&ap[r][c*8] = *(const uint4*)(wp + (size_t)(mt*96 + r)*C_ + ck + c*8);
            }
        }
        for (int s = tid; s < 512; s += 256) {
            int r = s >> 2, c4 = s & 3;
            *(uint4*)&B_s[r][c4*8] = *(const uint4*)(xsT + ((size_t)tb*L_ + l0 + r)*C_ + ck + c4*8);
        }
        __syncthreads();
        short8 bb[4];
#pragma unroll
        for (int in = 0; in < 4; in++)
            bb[in] = *(short8*)&B_s[lw + in*16 + n15][q*8];
#pragma unroll
        for (int im = 0; im < 3; im++) {
            short8 ah = *(short8*)&A_hi[mw + im*16 + n15][q*8];
            short8 am = *(short8*)&A_mi[mw + im*16 + n15][q*8];
            short8 al = *(short8*)&A_lo[mw + im*16 + n15][q*8];
#pragma unroll
            for (int in = 0; in < 4; in++) {
                acc[im][in] = __builtin_amdgcn_mfma_f32_16x16x32_bf16(ah, bb[in], acc[im][in], 0,0,0);
                acc[im][in] = __builtin_amdgcn_mfma_f32_16x16x32_bf16(am, bb[in], acc[im][in], 0,0,0);
                acc[im][in] = __builtin_amdgcn_mfma_f32_16x16x32_bf16(al, bb[in], acc[im][in], 0,0,0);
            }
        }
        __syncthreads();
    }

#pragma unroll
    for (int im = 0; im < 3; im++)
#pragma unroll
        for (int r = 0; r < 4; r++) {
            int o = mt*96 + mw + im*16 + q*4 + r;
            float inv = g[o] / sqrtf(vr[o] + 1e-5f);
            float sh = be[o] - mn[o]*inv;
#pragma unroll
            for (int in = 0; in < 4; in++)
                acc[im][in][r] = acc[im][in][r]*inv + sh;
        }
    const bool isY1 = ((w & 1) == 0);
#pragma unroll
    for (int p = 0; p < 3; p++) {
        if (isY1) {
#pragma unroll
            for (int im = 0; im < 3; im++)
#pragma unroll
                for (int in = 0; in < 4; in++) {
                    union { unsigned short us[4]; uint2 u2; } pk;
#pragma unroll
                    for (int r = 0; r < 4; r++) {
                        unsigned hh = bf16_rne(acc[im][in][r]);
                        pk.us[r] = (unsigned short)hh;
                        acc[im][in][r] -= bf16_to_f(hh);
                    }
                    *(uint2*)&epi1[(lw + in*16 + n15)*56 + im*16 + q*4] = pk.u2;
                }
        } else {
#pragma unroll
            for (int im = 0; im < 3; im++)
#pragma unroll
                for (int in = 0; in < 4; in++)
#pragma unroll
                    for (int r = 0; r < 4; r++) {
                        unsigned hh = bf16_rne(acc[im][in][r]);
                        epi2[(im*16 + q*4 + r)*136 + lw + in*16 + n15] = (unsigned short)hh;
                        acc[im][in][r] -= bf16_to_f(hh);
                    }
        }
        __syncthreads();
        unsigned short* y1p = p == 0 ? y1hi : p == 1 ? y1mi : y1lo;
        unsigned short* y2p = p == 0 ? y2hi : p == 1 ? y2mi : y2lo;
#pragma unroll
        for (int k2 = 0; k2 < 3; k2++) {
            int s = tid + k2*256;                      // s < 768
            int r1 = s / 6, c8 = s % 6;
            *(uint4*)(y1p + (((size_t)tb*H_ + mt)*L_ + l0 + r1)*48 + c8*8) =
                *(uint4*)&epi1[r1*56 + c8*8];
            int cr = s >> 4, lq = s & 15;
            *(uint4*)(y2p + ((size_t)tb*C_ + mt*48 + cr)*L_ + l0 + lq*8) =
                *(uint4*)&epi2[cr*136 + lq*8];
        }
        __syncthreads();
    }
}

// ============ K3: attn = y1^T @ xr (32x32x16 MFMA, K=48 exact) =============
// 1D grid 4096, XCD-swizzled: each XCD pinned to 2 (b,h) slices for L2 reuse
__global__ __launch_bounds__(256) void attn_spike_mfma(
    const unsigned short* __restrict__ y1hi, const unsigned short* __restrict__ y1mi,
    const unsigned short* __restrict__ y1lo, const unsigned short* __restrict__ xsT,
    unsigned* __restrict__ bits) {
    __shared__ unsigned short A_hi[64][56], A_mi[64][56], A_lo[64][56], B_s[64][56];
    __shared__ unsigned bits_s[64][2];
    const int tid = threadIdx.x;
    const int flat = blockIdx.x;
    const int xcd = flat & 7;
    const int ii = flat >> 3;                 // 0..511
    const int bh = xcd*2 + (ii >> 8);         // XCD-pinned (b,h)
    const int rr = ii & 255;
    const int b = bh >> 3, h = bh & 7;
    const int lbase = (rr >> 4)*64, mbase = (rr & 15)*64;
    const int w = tid >> 6, lane = tid & 63;
    const int l31 = lane & 31, half = lane >> 5;
    const int i = w & 1, j = w >> 1;

    float mem[16];
#pragma unroll
    for (int r = 0; r < 16; r++) mem[r] = 0.f;

    for (int t = 0; t < T_; t++) {
        const int tb = t*B_ + b;
        const size_t yb = (((size_t)tb*H_ + h)*L_ + lbase)*48;
        const size_t xb = ((size_t)tb*L_ + mbase)*C_ + h*48;
        for (int s = tid; s < 384; s += 256) {
            int r = s / 6, c = s % 6;
            size_t ro = yb + (size_t)r*48 + c*8;
            *(uint4*)&A_hi[r][c*8] = *(const uint4*)(y1hi + ro);
            *(uint4*)&A_mi[r][c*8] = *(const uint4*)(y1mi + ro);
            *(uint4*)&A_lo[r][c*8] = *(const uint4*)(y1lo + ro);
            *(uint4*)&B_s[r][c*8]  = *(const uint4*)(xsT + xb + (size_t)r*C_ + c*8);
        }
        if (tid < 128) bits_s[tid >> 1][tid & 1] = 0u;
        __syncthreads();

        floatx16 acc = {0.f,0.f,0.f,0.f,0.f,0.f,0.f,0.f,0.f,0.f,0.f,0.f,0.f,0.f,0.f,0.f};
#pragma unroll
        for (int ks = 0; ks < 3; ks++) {
            const int kcol = ks*16 + half*8;
            short8 bb = *(short8*)&B_s[j*32 + l31][kcol];
            short8 ah = *(short8*)&A_hi[i*32 + l31][kcol];
            short8 am = *(short8*)&A_mi[i*32 + l31][kcol];
            short8 al = *(short8*)&A_lo[i*32 + l31][kcol];
            acc = __builtin_amdgcn_mfma_f32_32x32x16_bf16(ah, bb, acc, 0,0,0);
            acc = __builtin_amdgcn_mfma_f32_32x32x16_bf16(am, bb, acc, 0,0,0);
            acc = __builtin_amdgcn_mfma_f32_32x32x16_bf16(al, bb, acc, 0,0,0);
        }

        unsigned word = 0;
#pragma unroll
        for (int r = 0; r < 16; r++) {
            float m = (mem[r] > 0.5f ? 0.f : mem[r]*0.25f) + acc[r];
            mem[r] = m;
            int lloc = (r & 3) + 8*(r >> 2) + 4*half;
            word |= (m > 0.5f) ? (1u << lloc) : 0u;
        }
        atomicOr(&bits_s[j*32 + l31][i], word);
        __syncthreads();
        if (tid < 128) {
            int m = tid >> 1, wd = tid & 1;
            bits[((size_t)(tb*H_ + h)*L_ + mbase + m)*32 + (lbase >> 5) + wd] = bits_s[m][wd];
        }
        __syncthreads();
    }
}

// ============ K4: outpre = y2 @ spikes (16x16x32, B unpacked from bits) ====
// 1D grid 1024, XCD-swizzled: each XCD pinned to 8 tbh slices
__global__ __launch_bounds__(256) void attn_out_mfma(
    const unsigned short* __restrict__ y2hi, const unsigned short* __restrict__ y2mi,
    const unsigned short* __restrict__ y2lo,
    const unsigned* __restrict__ bits, float* __restrict__ outpre) {
    __shared__ unsigned short A_hi[48][72], A_mi[48][72], A_lo[48][72];
    const int tid = threadIdx.x;
    const int flat = blockIdx.x;
    const int xcd = flat & 7;
    const int ii = flat >> 3;                 // 0..127
    const int tbh = xcd*8 + (ii >> 4);        // XCD-pinned tbh
    const int mtile = ii & 15;
    const int t = tbh >> 4, b = (tbh >> 3) & 1, h = tbh & 7;
    const int tb = t*B_ + b;
    const int w = tid >> 6, lane = tid & 63;
    const int q = lane >> 4, n15 = lane & 15;
    const int mb = mtile*64 + w*16;

    floatx4 acc[3];
#pragma unroll
    for (int i = 0; i < 3; i++) acc[i] = (floatx4){0.f,0.f,0.f,0.f};

    const unsigned* brow = bits + ((size_t)(tb*H_ + h)*L_ + mb + n15)*32;
    const size_t y2b = ((size_t)tb*C_ + h*48)*L_;

    for (int lt = 0; lt < L_; lt += 64) {
        for (int s = tid; s < 384; s += 256) {
            int r = s >> 3, c = s & 7;
            size_t ro = y2b + (size_t)r*L_ + lt + c*8;
            *(uint4*)&A_hi[r][c*8] = *(const uint4*)(y2hi + ro);
            *(uint4*)&A_mi[r][c*8] = *(const uint4*)(y2mi + ro);
            *(uint4*)&A_lo[r][c*8] = *(const uint4*)(y2lo + ro);
        }
        uint2 bw = *(const uint2*)(brow + (lt >> 5));
        __syncthreads();
#pragma unroll
        for (int kc = 0; kc < 2; kc++) {
            unsigned word = kc ? bw.y : bw.x;
            unsigned byt = (word >> (q*8)) & 0xFFu;
            union { unsigned u[4]; short8 v; } bu;
#pragma unroll
            for (int p = 0; p < 4; p++)
                bu.u[p] = (((byt >> (2*p)) & 1u) ? 0x3F80u : 0u)
                        | (((byt >> (2*p+1)) & 1u) ? 0x3F800000u : 0u);
            short8 bfrag = bu.v;
#pragma unroll
            for (int i = 0; i < 3; i++) {
                int ra = i*16 + n15;
                short8 ah = *(short8*)&A_hi[ra][kc*32 + q*8];
                short8 am = *(short8*)&A_mi[ra][kc*32 + q*8];
                short8 al = *(short8*)&A_lo[ra][kc*32 + q*8];
                acc[i] = __builtin_amdgcn_mfma_f32_16x16x32_bf16(ah, bfrag, acc[i], 0,0,0);
                acc[i] = __builtin_amdgcn_mfma_f32_16x16x32_bf16(am, bfrag, acc[i], 0,0,0);
                acc[i] = __builtin_amdgcn_mfma_f32_16x16x32_bf16(al, bfrag, acc[i], 0,0,0);
            }
        }
        __syncthreads();
    }
#pragma unroll
    for (int i = 0; i < 3; i++)
#pragma unroll
        for (int r = 0; r < 4; r++) {
            int d = i*16 + q*4 + r;
            outpre[((size_t)tb*C_ + h*48 + d)*L_ + mb + n15] = acc[i][r];
        }
}

// ============ K6: out = BN2(proj @ outs) + x (MFMA, 96x64 tile) ============
__global__ __launch_bounds__(256) void gemm2_mfma(
    const unsigned short* __restrict__ whi, const unsigned short* __restrict__ wmi,
    const unsigned short* __restrict__ wlo, const unsigned short* __restrict__ xT,
    const float* __restrict__ g, const float* __restrict__ be,
    const float* __restrict__ mn, const float* __restrict__ vr,
    const float* __restrict__ res, float* __restrict__ out) {
    __shared__ unsigned short A_hi[96][40], A_mi[96][40], A_lo[96][40];
    __shared__ unsigned short B_s[64][40];
    const int tid = threadIdx.x;
    const int tb = blockIdx.y;
    const int mt = blockIdx.x >> 4, lt = blockIdx.x & 15;
    const int l0 = lt * 64;
    const int w = tid >> 6, lane = tid & 63;
    const int q = lane >> 4, n15 = lane & 15;
    const int mw = (w & 1) * 48, lw = (w >> 1) * 32;

    floatx4 acc[3][2];
#pragma unroll
    for (int i = 0; i < 3; i++)
#pragma unroll
        for (int j = 0; j < 2; j++) acc[i][j] = (floatx4){0.f,0.f,0.f,0.f};

    for (int ck = 0; ck < C_; ck += 32) {
#pragma unroll
        for (int p = 0; p < 3; p++) {
            const unsigned short* wp = p == 0 ? whi : p == 1 ? wmi : wlo;
            unsigned short (*ap)[40] = p == 0 ? A_hi : p == 1 ? A_mi : A_lo;
            for (int s = tid; s < 384; s += 256) {
                int r = s >> 2, c = s & 3;
                *(uint4*)&ap[r][c*8] = *(const uint4*)(wp + (size_t)(mt*96 + r)*C_ + ck + c*8);
            }
        }
        {
            int r = tid >> 2, c4 = tid & 3;
            *(uint4*)&B_s[r][c4*8] = *(const uint4*)(xT + ((size_t)tb*L_ + l0 + r)*C_ + ck + c4*8);
        }
        __syncthreads();
        short8 bb[2];
#pragma unroll
        for (int in = 0; in < 2; in++)
            bb[in] = *(short8*)&B_s[lw + in*16 + n15][q*8];
#pragma unroll
        for (int im = 0; im < 3; im++) {
            short8 ah = *(short8*)&A_hi[mw + im*16 + n15][q*8];
            short8 am = *(short8*)&A_mi[mw + im*16 + n15][q*8];
            short8 al = *(short8*)&A_lo[mw + im*16 + n15][q*8];
#pragma unroll
            for (int in = 0; in < 2; in++) {
                acc[im][in] = __builtin_amdgcn_mfma_f32_16x16x32_bf16(ah, bb[in], acc[im][in], 0,0,0);
                acc[im][in] = __builtin_amdgcn_mfma_f32_16x16x32_bf16(am, bb[in], acc[im][in], 0,0,0);
                acc[im][in] = __builtin_amdgcn_mfma_f32_16x16x32_bf16(al, bb[in], acc[im][in], 0,0,0);
            }
        }
        __syncthreads();
    }
#pragma unroll
    for (int im = 0; im < 3; im++)
#pragma unroll
        for (int r = 0; r < 4; r++) {
            int o = mt*96 + mw + im*16 + q*4 + r;
            float inv = g[o] / sqrtf(vr[o] + 1e-5f);
            float sh = be[o] - mn[o]*inv;
#pragma unroll
            for (int in = 0; in < 2; in++) {
                int l = l0 + lw + in*16 + n15;
                size_t idx = ((size_t)tb*C_ + o)*L_ + l;
                out[idx] = acc[im][in][r]*inv + sh + res[idx];
            }
        }
}

extern "C" void kernel_launch(void* const* d_in, const int* in_sizes, int n_in,
                              void* d_out, int out_size, void* d_ws, size_t ws_size,
                              hipStream_t stream) {
    const float* x   = (const float*)d_in[0];
    const float* W_w = (const float*)d_in[1];
    const float* g1  = (const float*)d_in[2];
    const float* b1  = (const float*)d_in[3];
    const float* m1  = (const float*)d_in[4];
    const float* v1  = (const float*)d_in[5];
    const float* pw  = (const float*)d_in[6];
    const float* g2  = (const float*)d_in[7];
    const float* b2  = (const float*)d_in[8];
    const float* m2  = (const float*)d_in[9];
    const float* v2  = (const float*)d_in[10];

    float* ws = (float*)d_ws;
    unsigned short* xsT  = (unsigned short*)ws;               // 1,572,864 f
    unsigned short* y1hi = (unsigned short*)(ws + 1572864);   // 1,572,864 f each
    unsigned short* y1mi = (unsigned short*)(ws + 3145728);
    unsigned short* y1lo = (unsigned short*)(ws + 4718592);
    unsigned short* y2hi = (unsigned short*)(ws + 6291456);
    unsigned short* y2mi = (unsigned short*)(ws + 7864320);
    unsigned short* y2lo = (unsigned short*)(ws + 9437184);
    unsigned*       bits = (unsigned*)(ws + 11010048);        // ends 13,107,200 f
    unsigned short* wspl[3]  = {(unsigned short*)(ws + 13107200),
                                (unsigned short*)(ws + 13254656),
                                (unsigned short*)(ws + 13402112)};
    unsigned short* pwspl[3] = {(unsigned short*)(ws + 13549568),
                                (unsigned short*)(ws + 13623296),
                                (unsigned short*)(ws + 13697024)};  // ends 13,770,752 f = 55.1 MB
    float*          outpre = (float*)(ws + 1572864);          // alias y1hi+y1mi (dead after K3)
    unsigned short* outsT  = (unsigned short*)(ws + 4718592); // alias y1lo (dead after K3)
    float* out = (float*)d_out;

    // 0) split weights into bf16 planes (once per launch)
    split_w<<<dim3(288), 256, 0, stream>>>(W_w, C2_*C_/4, wspl[0], wspl[1], wspl[2]);
    split_w<<<dim3(144), 256, 0, stream>>>(pw,  C_*C_/4, pwspl[0], pwspl[1], pwspl[2]);
    // 1) xs spikes (exact fp32 scan) -> bf16, transposed [tb][l][c]
    scan_transpose<<<dim3(16, 6, B_), 256, 0, stream>>>(x, xsT);
    // 2) y = BN1(W @ xs): y1 compact [tb][h][l][48], y2 natural [tb][c][l]
    gemm1_mfma<<<dim3(64, 8), 256, 0, stream>>>(wspl[0], wspl[1], wspl[2], xsT,
                                                g1, b1, m1, v1,
                                                y1hi, y1mi, y1lo, y2hi, y2mi, y2lo);
    // 3) attn spikes: 32x32x16 MFMA, XCD-swizzled 1D grid
    attn_spike_mfma<<<dim3(4096), 256, 0, stream>>>(y1hi, y1mi, y1lo, xsT, bits);
    // 4) outpre = y2 @ spikes: MFMA, XCD-swizzled 1D grid
    attn_out_mfma<<<dim3(1024), 256, 0, stream>>>(y2hi, y2mi, y2lo, bits, outpre);
    // 5) outs spikes -> bf16 transposed
    scan_transpose<<<dim3(16, 6, B_), 256, 0, stream>>>(outpre, outsT);
    // 6) out = BN2(proj @ outs) + x
    gemm2_mfma<<<dim3(64, 8), 256, 0, stream>>>(pwspl[0], pwspl[1], pwspl[2], outsT,
                                                g2, b2, m2, v2, x, out);
}